// Round 2
// baseline (363.741 us; speedup 1.0000x reference)
//
#include <hip/hip_runtime.h>
#include <math.h>

#define D_MODEL 1024
#define NHEADS  16
#define HEADD   64
#define NFREQ   32
#define BATCH   2
#define CSEQ    2048
#define NROWS   (BATCH*CSEQ)   // 4096

typedef _Float16 half8 __attribute__((ext_vector_type(8)));
typedef float    f32x4 __attribute__((ext_vector_type(4)));

// ---------------------------------------------------------------------------
// cos/sin table: theta[c][f] = c * float32(freq_base_f64[f]); double precision
// to match numpy's float64 mel computation before fp32 cast.
// ---------------------------------------------------------------------------
__global__ __launch_bounds__(256) void build_cs_kernel(float2* __restrict__ cs)
{
    int i = blockIdx.x * 256 + threadIdx.x;
    if (i >= CSEQ * NFREQ) return;
    int c = i >> 5, f = i & (NFREQ - 1);
    double mel_max = 2595.0 * log10(21.0);   // log10(1 + 4000/200)
    double step    = mel_max / (double)(NFREQ - 1);
    double mel     = step * (double)f;
    double freq    = 200.0 * (pow(10.0, mel / 2595.0) - 1.0) / 1000.0;
    float fr = (float)freq;
    float th = (float)c * fr;
    float s, co;
    sincosf(th, &s, &co);
    cs[i] = make_float2(co, s);
}

// ---------------------------------------------------------------------------
// Transpose + cast fp32 (R x C) -> fp16 (C x R)
// ---------------------------------------------------------------------------
__global__ __launch_bounds__(256) void transpose_cast_kernel(
    const float* __restrict__ in, _Float16* __restrict__ out, int R, int C)
{
    __shared__ float t[32][33];
    int bx = blockIdx.x * 32;   // C offset
    int by = blockIdx.y * 32;   // R offset
    int tx = threadIdx.x, ty = threadIdx.y;
    #pragma unroll
    for (int i = ty; i < 32; i += 8)
        t[i][tx] = in[(size_t)(by + i) * C + bx + tx];
    __syncthreads();
    #pragma unroll
    for (int i = ty; i < 32; i += 8)
        out[(size_t)(bx + i) * R + by + tx] = (_Float16)t[tx][i];
}

// ---------------------------------------------------------------------------
// Fused: LN stats (shared by q-LN and kv-LN), per-row radius = clip(x.Wr/100)
// writes fp16 LN outputs for the MFMA GEMMs.
// ---------------------------------------------------------------------------
__global__ __launch_bounds__(256) void ln_radius_kernel(
    const float* __restrict__ x,
    const float* __restrict__ gq,  const float* __restrict__ bq,
    const float* __restrict__ gkv, const float* __restrict__ bkv,
    const float* __restrict__ Wr,  const float* __restrict__ br,
    _Float16* __restrict__ xq, _Float16* __restrict__ xkv,
    float* __restrict__ radius)
{
    int row = blockIdx.x;
    const float* xr = x + (size_t)row * D_MODEL;
    int tid = threadIdx.x;
    float v[4];
    float s = 0.f, ss = 0.f, dr = 0.f;
    #pragma unroll
    for (int i = 0; i < 4; ++i) {
        int idx = tid + i * 256;
        float t = xr[idx];
        v[i] = t;
        s += t; ss += t * t; dr += t * Wr[idx];
    }
    #pragma unroll
    for (int off = 1; off < 64; off <<= 1) {
        s  += __shfl_xor(s, off);
        ss += __shfl_xor(ss, off);
        dr += __shfl_xor(dr, off);
    }
    __shared__ float red[3][4];
    int w = tid >> 6, lane = tid & 63;
    if (lane == 0) { red[0][w] = s; red[1][w] = ss; red[2][w] = dr; }
    __syncthreads();
    s  = red[0][0] + red[0][1] + red[0][2] + red[0][3];
    ss = red[1][0] + red[1][1] + red[1][2] + red[1][3];
    float mean = s * (1.f / D_MODEL);
    float var  = ss * (1.f / D_MODEL) - mean * mean;
    float rinv = rsqrtf(var + 1e-5f);
    #pragma unroll
    for (int i = 0; i < 4; ++i) {
        int idx = tid + i * 256;
        float xn = (v[i] - mean) * rinv;
        xq [(size_t)row * D_MODEL + idx] = (_Float16)(xn * gq[idx]  + bq[idx]);
        xkv[(size_t)row * D_MODEL + idx] = (_Float16)(xn * gkv[idx] + bkv[idx]);
    }
    if (tid == 0) {
        float drt = red[2][0] + red[2][1] + red[2][2] + red[2][3];
        float p = (drt + br[0]) * 0.01f;
        radius[row] = fminf(fmaxf(p, 0.5f), 2.0f);
    }
}

// ---------------------------------------------------------------------------
// GEMM: C[m][n] = sum_k A[m][k]*BT[n][k] + bias[n].  fp16 in, fp32 out.
// 128x128 tile, BK=32, 4 waves (2x2), 16x16x32 MFMA. LDS stride 40 (2-way max).
// ---------------------------------------------------------------------------
#define BM 128
#define BN 128
#define BK 32
#define KP 40

__global__ __launch_bounds__(256) void gemm_bt_f16(
    const _Float16* __restrict__ A,   // M x K
    const _Float16* __restrict__ BT,  // N x K
    const float* __restrict__ bias,   // N
    float* __restrict__ C,            // M x N
    int M, int N, int K)
{
    __shared__ _Float16 As[BM][KP];
    __shared__ _Float16 Bs[BN][KP];
    int tid = threadIdx.x;
    int lane = tid & 63, w = tid >> 6;
    int wm = w >> 1, wn = w & 1;
    int l15 = lane & 15, lg = lane >> 4;
    int bm = blockIdx.x * BM;
    int bn = blockIdx.y * BN;
    int srow = tid >> 2;
    int sc8  = (tid & 3) * 8;
    f32x4 acc[4][4];
    f32x4 z = {0.f, 0.f, 0.f, 0.f};
    #pragma unroll
    for (int m = 0; m < 4; ++m)
        #pragma unroll
        for (int n = 0; n < 4; ++n) acc[m][n] = z;

    for (int k0 = 0; k0 < K; k0 += BK) {
        __syncthreads();
        #pragma unroll
        for (int h = 0; h < 2; ++h) {
            int r = srow + h * 64;
            *(half8*)&As[r][sc8] = *(const half8*)&A [(size_t)(bm + r) * K + k0 + sc8];
            *(half8*)&Bs[r][sc8] = *(const half8*)&BT[(size_t)(bn + r) * K + k0 + sc8];
        }
        __syncthreads();
        half8 af[4], bf[4];
        #pragma unroll
        for (int m = 0; m < 4; ++m) af[m] = *(const half8*)&As[wm * 64 + m * 16 + l15][lg * 8];
        #pragma unroll
        for (int n = 0; n < 4; ++n) bf[n] = *(const half8*)&Bs[wn * 64 + n * 16 + l15][lg * 8];
        #pragma unroll
        for (int m = 0; m < 4; ++m)
            #pragma unroll
            for (int n = 0; n < 4; ++n)
                acc[m][n] = __builtin_amdgcn_mfma_f32_16x16x32_f16(af[m], bf[n], acc[m][n], 0, 0, 0);
    }

    #pragma unroll
    for (int m = 0; m < 4; ++m) {
        int row = bm + wm * 64 + m * 16 + lg * 4;
        #pragma unroll
        for (int n = 0; n < 4; ++n) {
            int col = bn + wn * 64 + n * 16 + l15;
            float bb = bias[col];
            #pragma unroll
            for (int r = 0; r < 4; ++r)
                C[(size_t)(row + r) * N + col] = acc[m][n][r] + bb;
        }
    }
}

// ---------------------------------------------------------------------------
// Fused RoPE (polar, learned radius) + per-head LN for q and k.
// One wave handles one head-instance at a time: HD=64 == wavefront.
// ---------------------------------------------------------------------------
__global__ __launch_bounds__(256) void rope_headln_kernel(
    const float* __restrict__ q_raw,   // NROWS x 1024
    const float* __restrict__ kv_raw,  // NROWS x 2048
    const float* __restrict__ radius,
    const float2* __restrict__ cs_tab, // CSEQ x NFREQ
    const float* __restrict__ lnh_g, const float* __restrict__ lnh_b,
    _Float16* __restrict__ qn, _Float16* __restrict__ kn)  // (B,H,C,HD)
{
    int row = blockIdx.x;
    int b = row / CSEQ, c = row % CSEQ;
    int tid = threadIdx.x, lane = tid & 63, w = tid >> 6;
    float rr = radius[row];
    float2 cs = cs_tab[c * NFREQ + (lane >> 1)];
    float g = lnh_g[lane], bb = lnh_b[lane];

    #pragma unroll
    for (int hh = 0; hh < 4; ++hh) {
        int h = w * 4 + hh;
        size_t obase = ((size_t)(b * NHEADS + h) * CSEQ + c) * HEADD + lane;
        #pragma unroll
        for (int which = 0; which < 2; ++which) {
            float val = which == 0
                ? q_raw [(size_t)row * D_MODEL     + h * HEADD + lane]
                : kv_raw[(size_t)row * (2*D_MODEL) + h * HEADD + lane];
            float part = __shfl_xor(val, 1);
            float xr_ = (lane & 1) ? part : val;
            float xi_ = (lane & 1) ? val  : part;
            float rot = (lane & 1) ? rr * (xr_ * cs.y + xi_ * cs.x)
                                   : rr * (xr_ * cs.x - xi_ * cs.y);
            float s = rot;
            #pragma unroll
            for (int off = 1; off < 64; off <<= 1) s += __shfl_xor(s, off);
            float mean = s * (1.f / 64.f);
            float d = rot - mean;
            float ss = d * d;
            #pragma unroll
            for (int off = 1; off < 64; off <<= 1) ss += __shfl_xor(ss, off);
            float rinv = rsqrtf(ss * (1.f / 64.f) + 1e-5f);
            float o = d * rinv * g + bb;
            if (which == 0) qn[obase] = (_Float16)o;
            else            kn[obase] = (_Float16)o;
        }
    }
}

// ---------------------------------------------------------------------------
// V: (B,C, [v half of kv_raw]) -> vT fp16 (B,H,HD,C) via LDS transpose.
// ---------------------------------------------------------------------------
__global__ __launch_bounds__(256) void v_transpose_kernel(
    const float* __restrict__ kv_raw, _Float16* __restrict__ vT)
{
    int bh = blockIdx.x >> 5;
    int c0 = (blockIdx.x & 31) * 64;
    int b = bh >> 4, h = bh & 15;
    __shared__ float t[64][65];
    int tid = threadIdx.x;
    int dcol = tid & 63, quarter = tid >> 6;
    for (int c = quarter; c < 64; c += 4)
        t[c][dcol] = kv_raw[(size_t)(b * CSEQ + c0 + c) * (2*D_MODEL) + D_MODEL + h * HEADD + dcol];
    __syncthreads();
    for (int d = quarter; d < 64; d += 4)
        vT[(size_t)(bh * HEADD + d) * CSEQ + c0 + dcol] = (_Float16)t[dcol][d];
}

// ---------------------------------------------------------------------------
// Flash attention: 4 waves/block, each wave owns 64 q rows of one (b,h).
// K/V tiles (64 keys x 64 dims) staged in LDS shared by all 4 waves; P
// transposed through per-wave padded LDS for the PV MFMA. fp32 softmax.
// ---------------------------------------------------------------------------
__global__ __launch_bounds__(256, 1) void attn_kernel(
    const _Float16* __restrict__ qn, const _Float16* __restrict__ kn,
    const _Float16* __restrict__ vT, _Float16* __restrict__ o)
{
    __shared__ _Float16 Ks[64][72];
    __shared__ _Float16 Vs[64][72];
    __shared__ _Float16 P[4][64][72];
    int tid = threadIdx.x, lane = tid & 63, w = tid >> 6;
    int l15 = lane & 15, lg = lane >> 4;
    int bh = blockIdx.x >> 3;
    int q0 = ((blockIdx.x & 7) * 4 + w) * 64;
    const _Float16* qh = qn + (size_t)bh * CSEQ * HEADD;
    const _Float16* kh = kn + (size_t)bh * CSEQ * HEADD;
    const _Float16* vh = vT + (size_t)bh * HEADD * CSEQ;

    half8 aq[4][2];
    #pragma unroll
    for (int m = 0; m < 4; ++m)
        #pragma unroll
        for (int ks = 0; ks < 2; ++ks)
            aq[m][ks] = *(const half8*)&qh[(size_t)(q0 + m * 16 + l15) * HEADD + ks * 32 + lg * 8];

    f32x4 z = {0.f, 0.f, 0.f, 0.f};
    f32x4 oacc[4][4];
    float mrun[4][4], lrun[4][4];
    #pragma unroll
    for (int m = 0; m < 4; ++m)
        #pragma unroll
        for (int i = 0; i < 4; ++i) { oacc[m][i] = z; mrun[m][i] = -1e30f; lrun[m][i] = 0.f; }

    // staging: 64 rows x 64 cols = 4096 halves; 256 threads x 2 x half8
    int srow = tid >> 3;        // 0..31
    int sc8  = (tid & 7) * 8;   // 0..56

    for (int kt = 0; kt < CSEQ / 64; ++kt) {
        int k0 = kt * 64;
        __syncthreads();
        #pragma unroll
        for (int h = 0; h < 2; ++h) {
            int r = srow + h * 32;
            *(half8*)&Ks[r][sc8] = *(const half8*)&kh[(size_t)(k0 + r) * HEADD + sc8];
            *(half8*)&Vs[r][sc8] = *(const half8*)&vh[(size_t)r * CSEQ + k0 + sc8];
        }
        __syncthreads();

        f32x4 sacc[4][4];
        #pragma unroll
        for (int m = 0; m < 4; ++m)
            #pragma unroll
            for (int n = 0; n < 4; ++n) sacc[m][n] = z;

        #pragma unroll
        for (int ks = 0; ks < 2; ++ks) {
            half8 bk[4];
            #pragma unroll
            for (int n = 0; n < 4; ++n) bk[n] = *(const half8*)&Ks[n * 16 + l15][ks * 32 + lg * 8];
            #pragma unroll
            for (int m = 0; m < 4; ++m)
                #pragma unroll
                for (int n = 0; n < 4; ++n)
                    sacc[m][n] = __builtin_amdgcn_mfma_f32_16x16x32_f16(aq[m][ks], bk[n], sacc[m][n], 0, 0, 0);
        }

        #pragma unroll
        for (int m = 0; m < 4; ++m) {
            #pragma unroll
            for (int n = 0; n < 4; ++n) sacc[m][n] *= 0.125f;
            #pragma unroll
            for (int r = 0; r < 4; ++r) {
                float tmax = fmaxf(fmaxf(sacc[m][0][r], sacc[m][1][r]),
                                   fmaxf(sacc[m][2][r], sacc[m][3][r]));
                #pragma unroll
                for (int off = 1; off < 16; off <<= 1) tmax = fmaxf(tmax, __shfl_xor(tmax, off));
                float nm = fmaxf(mrun[m][r], tmax);
                float sc_ = __expf(mrun[m][r] - nm);
                mrun[m][r] = nm;
                float ps = 0.f;
                #pragma unroll
                for (int n = 0; n < 4; ++n) {
                    float p = __expf(sacc[m][n][r] - nm);
                    sacc[m][n][r] = p;
                    ps += p;
                }
                #pragma unroll
                for (int off = 1; off < 16; off <<= 1) ps += __shfl_xor(ps, off);
                lrun[m][r] = lrun[m][r] * sc_ + ps;
                #pragma unroll
                for (int d4 = 0; d4 < 4; ++d4) oacc[m][d4][r] *= sc_;
            }
            #pragma unroll
            for (int n = 0; n < 4; ++n)
                #pragma unroll
                for (int r = 0; r < 4; ++r)
                    P[w][m * 16 + lg * 4 + r][n * 16 + l15] = (_Float16)sacc[m][n][r];
        }
        __syncthreads();

        #pragma unroll
        for (int ks = 0; ks < 2; ++ks) {
            half8 ap[4], bv[4];
            #pragma unroll
            for (int m = 0; m < 4; ++m) ap[m] = *(const half8*)&P[w][m * 16 + l15][ks * 32 + lg * 8];
            #pragma unroll
            for (int d4 = 0; d4 < 4; ++d4) bv[d4] = *(const half8*)&Vs[d4 * 16 + l15][ks * 32 + lg * 8];
            #pragma unroll
            for (int m = 0; m < 4; ++m)
                #pragma unroll
                for (int d4 = 0; d4 < 4; ++d4)
                    oacc[m][d4] = __builtin_amdgcn_mfma_f32_16x16x32_f16(ap[m], bv[d4], oacc[m][d4], 0, 0, 0);
        }
    }

    int b = bh >> 4, h = bh & 15;
    #pragma unroll
    for (int m = 0; m < 4; ++m)
        #pragma unroll
        for (int r = 0; r < 4; ++r) {
            float inv = 1.f / lrun[m][r];
            int c = q0 + m * 16 + lg * 4 + r;
            size_t base = ((size_t)b * CSEQ + c) * D_MODEL + h * HEADD;
            #pragma unroll
            for (int d4 = 0; d4 < 4; ++d4)
                o[base + d4 * 16 + l15] = (_Float16)(oacc[m][d4][r] * inv);
        }
}

// ---------------------------------------------------------------------------
extern "C" void kernel_launch(void* const* d_in, const int* in_sizes, int n_in,
                              void* d_out, int out_size, void* d_ws, size_t ws_size,
                              hipStream_t stream)
{
    (void)in_sizes; (void)n_in; (void)out_size; (void)ws_size;
    const float* x      = (const float*)d_in[0];
    const float* ln_q_g = (const float*)d_in[1];
    const float* ln_q_b = (const float*)d_in[2];
    const float* Wq     = (const float*)d_in[3];
    const float* bq     = (const float*)d_in[4];
    const float* ln_kv_g= (const float*)d_in[5];
    const float* ln_kv_b= (const float*)d_in[6];
    const float* Wkv    = (const float*)d_in[7];
    const float* bkv    = (const float*)d_in[8];
    const float* Wout   = (const float*)d_in[9];
    const float* bout   = (const float*)d_in[10];
    const float* lnh_g  = (const float*)d_in[11];
    const float* lnh_b  = (const float*)d_in[12];
    const float* Wr     = (const float*)d_in[13];
    const float* br     = (const float*)d_in[14];
    float* out = (float*)d_out;

    char* ws = (char*)d_ws;
    size_t off = 0;
    auto alloc = [&](size_t bytes) -> void* {
        void* p = ws + off;
        off += (bytes + 255) & ~(size_t)255;
        return p;
    };
    _Float16* WqT   = (_Float16*)alloc((size_t)D_MODEL * D_MODEL * 2);
    _Float16* WkvT  = (_Float16*)alloc((size_t)2 * D_MODEL * D_MODEL * 2);
    _Float16* WoutT = (_Float16*)alloc((size_t)D_MODEL * D_MODEL * 2);
    float*    radius= (float*)   alloc((size_t)NROWS * 4);
    float2*   cs_tab= (float2*)  alloc((size_t)CSEQ * NFREQ * 8);
    _Float16* vT    = (_Float16*)alloc((size_t)BATCH * NHEADS * HEADD * CSEQ * 2);
    float*    kv_raw= (float*)   alloc((size_t)NROWS * 2 * D_MODEL * 4);
    // region A: xq (fp16) -> later qn (same size)
    _Float16* xq    = (_Float16*)alloc((size_t)NROWS * D_MODEL * 2);
    _Float16* qn    = xq;
    // region B: xkv -> later kn
    _Float16* xkv   = (_Float16*)alloc((size_t)NROWS * D_MODEL * 2);
    _Float16* kn    = xkv;
    // region C: q_raw (fp32, 16MB) -> later o_h (fp16, 8MB)
    float*    q_raw = (float*)   alloc((size_t)NROWS * D_MODEL * 4);
    _Float16* o_h   = (_Float16*)q_raw;

    hipLaunchKernelGGL(build_cs_kernel, dim3(CSEQ * NFREQ / 256), dim3(256), 0, stream, cs_tab);
    hipLaunchKernelGGL(transpose_cast_kernel, dim3(D_MODEL/32, D_MODEL/32), dim3(32, 8), 0, stream,
                       Wq, WqT, D_MODEL, D_MODEL);
    hipLaunchKernelGGL(transpose_cast_kernel, dim3(2*D_MODEL/32, D_MODEL/32), dim3(32, 8), 0, stream,
                       Wkv, WkvT, D_MODEL, 2*D_MODEL);
    hipLaunchKernelGGL(transpose_cast_kernel, dim3(D_MODEL/32, D_MODEL/32), dim3(32, 8), 0, stream,
                       Wout, WoutT, D_MODEL, D_MODEL);
    hipLaunchKernelGGL(ln_radius_kernel, dim3(NROWS), dim3(256), 0, stream,
                       x, ln_q_g, ln_q_b, ln_kv_g, ln_kv_b, Wr, br, xq, xkv, radius);
    hipLaunchKernelGGL(gemm_bt_f16, dim3(NROWS/BM, D_MODEL/BN), dim3(256), 0, stream,
                       xq, WqT, bq, q_raw, NROWS, D_MODEL, D_MODEL);
    hipLaunchKernelGGL(gemm_bt_f16, dim3(NROWS/BM, 2*D_MODEL/BN), dim3(256), 0, stream,
                       xkv, WkvT, bkv, kv_raw, NROWS, 2*D_MODEL, D_MODEL);
    hipLaunchKernelGGL(rope_headln_kernel, dim3(NROWS), dim3(256), 0, stream,
                       q_raw, kv_raw, radius, cs_tab, lnh_g, lnh_b, qn, kn);
    hipLaunchKernelGGL(v_transpose_kernel, dim3(BATCH*NHEADS*CSEQ/64), dim3(256), 0, stream,
                       kv_raw, vT);
    hipLaunchKernelGGL(attn_kernel, dim3(BATCH*NHEADS*CSEQ/256), dim3(256), 0, stream,
                       qn, kn, vT, o_h);
    hipLaunchKernelGGL(gemm_bt_f16, dim3(NROWS/BM, D_MODEL/BN), dim3(256), 0, stream,
                       o_h, WoutT, bout, out, NROWS, D_MODEL, D_MODEL);
}

// Round 3
// 261.472 us; speedup vs baseline: 1.3911x; 1.3911x over previous
//
#include <hip/hip_runtime.h>
#include <math.h>

#define D_MODEL 1024
#define NHEADS  16
#define HEADD   64
#define NFREQ   32
#define BATCH   2
#define CSEQ    2048
#define NROWS   (BATCH*CSEQ)   // 4096

typedef _Float16 half8 __attribute__((ext_vector_type(8)));
typedef float    f32x4 __attribute__((ext_vector_type(4)));

// async global->LDS, 16B per lane. dest is WAVE-UNIFORM base (HW adds lane*16).
__device__ __forceinline__ void async16(void* lds, const void* g)
{
    __builtin_amdgcn_global_load_lds((const __attribute__((address_space(1))) unsigned int*)g,
                                     (__attribute__((address_space(3))) unsigned int*)lds,
                                     16, 0, 0);
}

// ---------------------------------------------------------------------------
// cos/sin table (double precision mel to match numpy f64 -> f32 cast)
// ---------------------------------------------------------------------------
__global__ __launch_bounds__(256) void build_cs_kernel(float2* __restrict__ cs)
{
    int i = blockIdx.x * 256 + threadIdx.x;
    if (i >= CSEQ * NFREQ) return;
    int c = i >> 5, f = i & (NFREQ - 1);
    double mel_max = 2595.0 * log10(21.0);
    double step    = mel_max / (double)(NFREQ - 1);
    double freq    = 200.0 * (pow(10.0, step * (double)f / 2595.0) - 1.0) / 1000.0;
    float fr = (float)freq;
    float th = (float)c * fr;
    float s, co;
    sincosf(th, &s, &co);
    cs[i] = make_float2(co, s);
}

// ---------------------------------------------------------------------------
// Transpose + cast fp32 (R x C) -> fp16 (C x R)
// ---------------------------------------------------------------------------
__global__ __launch_bounds__(256) void transpose_cast_kernel(
    const float* __restrict__ in, _Float16* __restrict__ out, int R, int C)
{
    __shared__ float t[32][33];
    int bx = blockIdx.x * 32;
    int by = blockIdx.y * 32;
    int tx = threadIdx.x, ty = threadIdx.y;
    #pragma unroll
    for (int i = ty; i < 32; i += 8)
        t[i][tx] = in[(size_t)(by + i) * C + bx + tx];
    __syncthreads();
    #pragma unroll
    for (int i = ty; i < 32; i += 8)
        out[(size_t)(bx + i) * R + by + tx] = (_Float16)t[tx][i];
}

// ---------------------------------------------------------------------------
// Fused LN (shared stats for q-LN / kv-LN) + radius
// ---------------------------------------------------------------------------
__global__ __launch_bounds__(256) void ln_radius_kernel(
    const float* __restrict__ x,
    const float* __restrict__ gq,  const float* __restrict__ bq,
    const float* __restrict__ gkv, const float* __restrict__ bkv,
    const float* __restrict__ Wr,  const float* __restrict__ br,
    _Float16* __restrict__ xq, _Float16* __restrict__ xkv,
    float* __restrict__ radius)
{
    int row = blockIdx.x;
    const float* xr = x + (size_t)row * D_MODEL;
    int tid = threadIdx.x;
    float v[4];
    float s = 0.f, ss = 0.f, dr = 0.f;
    #pragma unroll
    for (int i = 0; i < 4; ++i) {
        int idx = tid + i * 256;
        float t = xr[idx];
        v[i] = t;
        s += t; ss += t * t; dr += t * Wr[idx];
    }
    #pragma unroll
    for (int off = 1; off < 64; off <<= 1) {
        s  += __shfl_xor(s, off);
        ss += __shfl_xor(ss, off);
        dr += __shfl_xor(dr, off);
    }
    __shared__ float red[3][4];
    int w = tid >> 6, lane = tid & 63;
    if (lane == 0) { red[0][w] = s; red[1][w] = ss; red[2][w] = dr; }
    __syncthreads();
    s  = red[0][0] + red[0][1] + red[0][2] + red[0][3];
    ss = red[1][0] + red[1][1] + red[1][2] + red[1][3];
    float mean = s * (1.f / D_MODEL);
    float var  = ss * (1.f / D_MODEL) - mean * mean;
    float rinv = rsqrtf(var + 1e-5f);
    #pragma unroll
    for (int i = 0; i < 4; ++i) {
        int idx = tid + i * 256;
        float xn = (v[i] - mean) * rinv;
        xq [(size_t)row * D_MODEL + idx] = (_Float16)(xn * gq[idx]  + bq[idx]);
        xkv[(size_t)row * D_MODEL + idx] = (_Float16)(xn * gkv[idx] + bkv[idx]);
    }
    if (tid == 0) {
        float drt = red[2][0] + red[2][1] + red[2][2] + red[2][3];
        float p = (drt + br[0]) * 0.01f;
        radius[row] = fminf(fmaxf(p, 0.5f), 2.0f);
    }
}

// ---------------------------------------------------------------------------
// GEMM: C = A * BT^T + bias. 128x128 tile, BK=32, global_load_lds staging,
// linear LDS [128][32] (64B rows: fragment reads are conflict-balanced).
// ---------------------------------------------------------------------------
#define BM 128
#define BN 128
#define BK 32

__global__ __launch_bounds__(256) void gemm_bt_f16(
    const _Float16* __restrict__ A,   // M x K
    const _Float16* __restrict__ BT,  // N x K
    const float* __restrict__ bias,   // N
    float* __restrict__ C,            // M x N
    int M, int N, int K)
{
    __shared__ _Float16 As[BM * BK];
    __shared__ _Float16 Bs[BN * BK];
    int tid = threadIdx.x;
    int lane = tid & 63, w = tid >> 6;
    int wm = w >> 1, wn = w & 1;
    int l15 = lane & 15, lg = lane >> 4;
    int bm = blockIdx.x * BM;
    int bn = blockIdx.y * BN;
    int lrow = lane >> 2;        // 0..15 within segment
    int lch  = lane & 3;         // 16B chunk within 64B row
    f32x4 acc[4][4];
    f32x4 z = {0.f, 0.f, 0.f, 0.f};
    #pragma unroll
    for (int m = 0; m < 4; ++m)
        #pragma unroll
        for (int n = 0; n < 4; ++n) acc[m][n] = z;

    for (int k0 = 0; k0 < K; k0 += BK) {
        __syncthreads();
        #pragma unroll
        for (int i = 0; i < 2; ++i) {
            int seg = w * 2 + i;              // 0..7, 16 rows each
            int row = seg * 16 + lrow;
            async16(&As[seg * 512], &A [(size_t)(bm + row) * K + k0 + lch * 8]);
            async16(&Bs[seg * 512], &BT[(size_t)(bn + row) * K + k0 + lch * 8]);
        }
        __syncthreads();
        half8 af[4], bf[4];
        #pragma unroll
        for (int m = 0; m < 4; ++m) af[m] = *(const half8*)&As[(wm * 64 + m * 16 + l15) * BK + lg * 8];
        #pragma unroll
        for (int n = 0; n < 4; ++n) bf[n] = *(const half8*)&Bs[(wn * 64 + n * 16 + l15) * BK + lg * 8];
        #pragma unroll
        for (int m = 0; m < 4; ++m)
            #pragma unroll
            for (int n = 0; n < 4; ++n)
                acc[m][n] = __builtin_amdgcn_mfma_f32_16x16x32_f16(af[m], bf[n], acc[m][n], 0, 0, 0);
    }

    #pragma unroll
    for (int m = 0; m < 4; ++m) {
        int row = bm + wm * 64 + m * 16 + lg * 4;
        #pragma unroll
        for (int n = 0; n < 4; ++n) {
            int col = bn + wn * 64 + n * 16 + l15;
            float bb = bias[col];
            #pragma unroll
            for (int r = 0; r < 4; ++r)
                C[(size_t)(row + r) * N + col] = acc[m][n][r] + bb;
        }
    }
}

// ---------------------------------------------------------------------------
// Fused RoPE + per-head LN (HD=64 == wave)
// ---------------------------------------------------------------------------
__global__ __launch_bounds__(256) void rope_headln_kernel(
    const float* __restrict__ q_raw,
    const float* __restrict__ kv_raw,
    const float* __restrict__ radius,
    const float2* __restrict__ cs_tab,
    const float* __restrict__ lnh_g, const float* __restrict__ lnh_b,
    _Float16* __restrict__ qn, _Float16* __restrict__ kn)
{
    int row = blockIdx.x;
    int b = row / CSEQ, c = row % CSEQ;
    int tid = threadIdx.x, lane = tid & 63, w = tid >> 6;
    float rr = radius[row];
    float2 cs = cs_tab[c * NFREQ + (lane >> 1)];
    float g = lnh_g[lane], bb = lnh_b[lane];

    #pragma unroll
    for (int hh = 0; hh < 4; ++hh) {
        int h = w * 4 + hh;
        size_t obase = ((size_t)(b * NHEADS + h) * CSEQ + c) * HEADD + lane;
        #pragma unroll
        for (int which = 0; which < 2; ++which) {
            float val = which == 0
                ? q_raw [(size_t)row * D_MODEL     + h * HEADD + lane]
                : kv_raw[(size_t)row * (2*D_MODEL) + h * HEADD + lane];
            float part = __shfl_xor(val, 1);
            float xr_ = (lane & 1) ? part : val;
            float xi_ = (lane & 1) ? val  : part;
            float rot = (lane & 1) ? rr * (xr_ * cs.y + xi_ * cs.x)
                                   : rr * (xr_ * cs.x - xi_ * cs.y);
            float s = rot;
            #pragma unroll
            for (int off = 1; off < 64; off <<= 1) s += __shfl_xor(s, off);
            float mean = s * (1.f / 64.f);
            float d = rot - mean;
            float ss = d * d;
            #pragma unroll
            for (int off = 1; off < 64; off <<= 1) ss += __shfl_xor(ss, off);
            float rinv = rsqrtf(ss * (1.f / 64.f) + 1e-5f);
            float o = d * rinv * g + bb;
            if (which == 0) qn[obase] = (_Float16)o;
            else            kn[obase] = (_Float16)o;
        }
    }
}

// ---------------------------------------------------------------------------
// V -> vT fp16 (B,H,HD,C)
// ---------------------------------------------------------------------------
__global__ __launch_bounds__(256) void v_transpose_kernel(
    const float* __restrict__ kv_raw, _Float16* __restrict__ vT)
{
    int bh = blockIdx.x >> 5;
    int c0 = (blockIdx.x & 31) * 64;
    int b = bh >> 4, h = bh & 15;
    __shared__ float t[64][65];
    int tid = threadIdx.x;
    int dcol = tid & 63, quarter = tid >> 6;
    for (int c = quarter; c < 64; c += 4)
        t[c][dcol] = kv_raw[(size_t)(b * CSEQ + c0 + c) * (2*D_MODEL) + D_MODEL + h * HEADD + dcol];
    __syncthreads();
    for (int d = quarter; d < 64; d += 4)
        vT[(size_t)(bh * HEADD + d) * CSEQ + c0 + dcol] = (_Float16)t[dcol][d];
}

// ---------------------------------------------------------------------------
// Flash attention. Grid 512 (XCD-chunk swizzled), 4 waves/block, each wave
// 32 q-rows. K/V double-buffered via global_load_lds with pre-swizzled
// global source (XOR-16B within 8-row stripes) -> conflict-balanced b128
// fragment reads. One barrier per K-tile.
// ---------------------------------------------------------------------------
#define KVB 64
#define NT  (CSEQ / KVB)

__global__ __launch_bounds__(256) void attn_kernel(
    const _Float16* __restrict__ qn, const _Float16* __restrict__ kn,
    const _Float16* __restrict__ vT, _Float16* __restrict__ o)
{
    __shared__ _Float16 KsB[2][KVB * 64];
    __shared__ _Float16 VsB[2][KVB * 64];
    __shared__ _Float16 P[4][32][72];
    int tid = threadIdx.x, lane = tid & 63, w = tid >> 6;
    int l15 = lane & 15, lg = lane >> 4;

    // bijective XCD-chunk swizzle: 16 consecutive work-items (one bh) per XCD chunk
    int orig = blockIdx.x;                 // grid = 512, 512 % 8 == 0
    int wg   = (orig & 7) * 64 + (orig >> 3);
    int bh   = wg >> 4;
    int qc   = wg & 15;
    int q0   = qc * 128 + w * 32;

    const _Float16* qh = qn + (size_t)bh * CSEQ * HEADD;
    const _Float16* kh = kn + (size_t)bh * CSEQ * HEADD;
    const _Float16* vh = vT + (size_t)bh * HEADD * CSEQ;

    half8 aq[2][2];
    #pragma unroll
    for (int m = 0; m < 2; ++m)
        #pragma unroll
        for (int ks = 0; ks < 2; ++ks)
            aq[m][ks] = *(const half8*)&qh[(size_t)(q0 + m * 16 + l15) * HEADD + ks * 32 + lg * 8];

    f32x4 z = {0.f, 0.f, 0.f, 0.f};
    f32x4 oacc[2][4];
    float mrun[2][4], lrun[2][4];
    #pragma unroll
    for (int m = 0; m < 2; ++m)
        #pragma unroll
        for (int i = 0; i < 4; ++i) { oacc[m][i] = z; mrun[m][i] = -1e30f; lrun[m][i] = 0.f; }

    // staging geometry: 8 segments of 8 rows (1KB each) per 64x64 tile;
    // lane l -> row seg*8 + (l>>3), source chunk (l&7) ^ (l>>3)  (XOR swizzle)
    int srow_in = lane >> 3;                       // 0..7
    int csrc    = (lane & 7) ^ srow_in;            // swizzled 16B chunk

    auto stage = [&](int buf, int kt) {
        int k0 = kt * KVB;
        #pragma unroll
        for (int i = 0; i < 2; ++i) {
            int seg = w * 2 + i;                   // 0..7
            int r = seg * 8 + srow_in;
            async16(&KsB[buf][seg * 512], &kh[(size_t)(k0 + r) * HEADD + csrc * 8]);
            async16(&VsB[buf][seg * 512], &vh[(size_t)r * CSEQ + k0 + csrc * 8]);
        }
    };

    stage(0, 0);
    __syncthreads();            // drains vmcnt(0) + barrier
    int cur = 0;

    for (int kt = 0; kt < NT; ++kt) {
        if (kt + 1 < NT) stage(cur ^ 1, kt + 1);

        // ---- QK^T ----
        f32x4 sacc[2][4];
        #pragma unroll
        for (int m = 0; m < 2; ++m)
            #pragma unroll
            for (int n = 0; n < 4; ++n) sacc[m][n] = z;

        #pragma unroll
        for (int ks = 0; ks < 2; ++ks) {
            half8 bk[4];
            #pragma unroll
            for (int n = 0; n < 4; ++n) {
                int row = n * 16 + l15;
                int ch = (ks * 4 + lg) ^ (row & 7);
                bk[n] = *(const half8*)&KsB[cur][row * 64 + ch * 8];
            }
            #pragma unroll
            for (int m = 0; m < 2; ++m)
                #pragma unroll
                for (int n = 0; n < 4; ++n)
                    sacc[m][n] = __builtin_amdgcn_mfma_f32_16x16x32_f16(aq[m][ks], bk[n], sacc[m][n], 0, 0, 0);
        }

        // ---- online softmax ----
        #pragma unroll
        for (int m = 0; m < 2; ++m) {
            #pragma unroll
            for (int n = 0; n < 4; ++n) sacc[m][n] *= 0.125f;
            #pragma unroll
            for (int r = 0; r < 4; ++r) {
                float tmax = fmaxf(fmaxf(sacc[m][0][r], sacc[m][1][r]),
                                   fmaxf(sacc[m][2][r], sacc[m][3][r]));
                #pragma unroll
                for (int off = 1; off < 16; off <<= 1) tmax = fmaxf(tmax, __shfl_xor(tmax, off));
                float nm = fmaxf(mrun[m][r], tmax);
                float sc_ = __expf(mrun[m][r] - nm);
                mrun[m][r] = nm;
                float ps = 0.f;
                #pragma unroll
                for (int n = 0; n < 4; ++n) {
                    float p = __expf(sacc[m][n][r] - nm);
                    sacc[m][n][r] = p;
                    ps += p;
                }
                #pragma unroll
                for (int off = 1; off < 16; off <<= 1) ps += __shfl_xor(ps, off);
                lrun[m][r] = lrun[m][r] * sc_ + ps;
                #pragma unroll
                for (int d4 = 0; d4 < 4; ++d4) oacc[m][d4][r] *= sc_;
            }
            #pragma unroll
            for (int n = 0; n < 4; ++n)
                #pragma unroll
                for (int r = 0; r < 4; ++r)
                    P[w][m * 16 + lg * 4 + r][n * 16 + l15] = (_Float16)sacc[m][n][r];
        }
        // P is wave-private: no barrier needed (compiler handles lgkmcnt)

        // ---- PV ----
        #pragma unroll
        for (int ks = 0; ks < 2; ++ks) {
            half8 ap[2], bv[4];
            #pragma unroll
            for (int m = 0; m < 2; ++m)
                ap[m] = *(const half8*)&P[w][m * 16 + l15][ks * 32 + lg * 8];
            #pragma unroll
            for (int d4 = 0; d4 < 4; ++d4) {
                int row = d4 * 16 + l15;
                int ch = (ks * 4 + lg) ^ (row & 7);
                bv[d4] = *(const half8*)&VsB[cur][row * 64 + ch * 8];
            }
            #pragma unroll
            for (int m = 0; m < 2; ++m)
                #pragma unroll
                for (int d4 = 0; d4 < 4; ++d4)
                    oacc[m][d4] = __builtin_amdgcn_mfma_f32_16x16x32_f16(ap[m], bv[d4], oacc[m][d4], 0, 0, 0);
        }

        __syncthreads();        // drains stage(kt+1) vmcnt + protects cur buffers
        cur ^= 1;
    }

    int b = bh >> 4, h = bh & 15;
    #pragma unroll
    for (int m = 0; m < 2; ++m)
        #pragma unroll
        for (int r = 0; r < 4; ++r) {
            float inv = 1.f / lrun[m][r];
            int c = q0 + m * 16 + lg * 4 + r;
            size_t base = ((size_t)b * CSEQ + c) * D_MODEL + h * HEADD;
            #pragma unroll
            for (int d4 = 0; d4 < 4; ++d4)
                o[base + d4 * 16 + l15] = (_Float16)(oacc[m][d4][r] * inv);
        }
}

// ---------------------------------------------------------------------------
extern "C" void kernel_launch(void* const* d_in, const int* in_sizes, int n_in,
                              void* d_out, int out_size, void* d_ws, size_t ws_size,
                              hipStream_t stream)
{
    (void)in_sizes; (void)n_in; (void)out_size; (void)ws_size;
    const float* x      = (const float*)d_in[0];
    const float* ln_q_g = (const float*)d_in[1];
    const float* ln_q_b = (const float*)d_in[2];
    const float* Wq     = (const float*)d_in[3];
    const float* bq     = (const float*)d_in[4];
    const float* ln_kv_g= (const float*)d_in[5];
    const float* ln_kv_b= (const float*)d_in[6];
    const float* Wkv    = (const float*)d_in[7];
    const float* bkv    = (const float*)d_in[8];
    const float* Wout   = (const float*)d_in[9];
    const float* bout   = (const float*)d_in[10];
    const float* lnh_g  = (const float*)d_in[11];
    const float* lnh_b  = (const float*)d_in[12];
    const float* Wr     = (const float*)d_in[13];
    const float* br     = (const float*)d_in[14];
    float* out = (float*)d_out;

    char* ws = (char*)d_ws;
    size_t off = 0;
    auto alloc = [&](size_t bytes) -> void* {
        void* p = ws + off;
        off += (bytes + 255) & ~(size_t)255;
        return p;
    };
    _Float16* WqT   = (_Float16*)alloc((size_t)D_MODEL * D_MODEL * 2);
    _Float16* WkvT  = (_Float16*)alloc((size_t)2 * D_MODEL * D_MODEL * 2);
    _Float16* WoutT = (_Float16*)alloc((size_t)D_MODEL * D_MODEL * 2);
    float*    radius= (float*)   alloc((size_t)NROWS * 4);
    float2*   cs_tab= (float2*)  alloc((size_t)CSEQ * NFREQ * 8);
    _Float16* vT    = (_Float16*)alloc((size_t)BATCH * NHEADS * HEADD * CSEQ * 2);
    float*    kv_raw= (float*)   alloc((size_t)NROWS * 2 * D_MODEL * 4);
    _Float16* xq    = (_Float16*)alloc((size_t)NROWS * D_MODEL * 2);
    _Float16* qn    = xq;
    _Float16* xkv   = (_Float16*)alloc((size_t)NROWS * D_MODEL * 2);
    _Float16* kn    = xkv;
    float*    q_raw = (float*)   alloc((size_t)NROWS * D_MODEL * 4);
    _Float16* o_h   = (_Float16*)q_raw;

    hipLaunchKernelGGL(build_cs_kernel, dim3(CSEQ * NFREQ / 256), dim3(256), 0, stream, cs_tab);
    hipLaunchKernelGGL(transpose_cast_kernel, dim3(D_MODEL/32, D_MODEL/32), dim3(32, 8), 0, stream,
                       Wq, WqT, D_MODEL, D_MODEL);
    hipLaunchKernelGGL(transpose_cast_kernel, dim3(2*D_MODEL/32, D_MODEL/32), dim3(32, 8), 0, stream,
                       Wkv, WkvT, D_MODEL, 2*D_MODEL);
    hipLaunchKernelGGL(transpose_cast_kernel, dim3(D_MODEL/32, D_MODEL/32), dim3(32, 8), 0, stream,
                       Wout, WoutT, D_MODEL, D_MODEL);
    hipLaunchKernelGGL(ln_radius_kernel, dim3(NROWS), dim3(256), 0, stream,
                       x, ln_q_g, ln_q_b, ln_kv_g, ln_kv_b, Wr, br, xq, xkv, radius);
    hipLaunchKernelGGL(gemm_bt_f16, dim3(NROWS/BM, D_MODEL/BN), dim3(256), 0, stream,
                       xq, WqT, bq, q_raw, NROWS, D_MODEL, D_MODEL);
    hipLaunchKernelGGL(gemm_bt_f16, dim3(NROWS/BM, 2*D_MODEL/BN), dim3(256), 0, stream,
                       xkv, WkvT, bkv, kv_raw, NROWS, 2*D_MODEL, D_MODEL);
    hipLaunchKernelGGL(rope_headln_kernel, dim3(NROWS), dim3(256), 0, stream,
                       q_raw, kv_raw, radius, cs_tab, lnh_g, lnh_b, qn, kn);
    hipLaunchKernelGGL(v_transpose_kernel, dim3(BATCH*NHEADS*CSEQ/64), dim3(256), 0, stream,
                       kv_raw, vT);
    hipLaunchKernelGGL(attn_kernel, dim3(BATCH*NHEADS*CSEQ/128), dim3(256), 0, stream,
                       qn, kn, vT, o_h);
    hipLaunchKernelGGL(gemm_bt_f16, dim3(NROWS/BM, D_MODEL/BN), dim3(256), 0, stream,
                       o_h, WoutT, bout, out, NROWS, D_MODEL, D_MODEL);
}

// Round 4
// 195.781 us; speedup vs baseline: 1.8579x; 1.3355x over previous
//
#include <hip/hip_runtime.h>
#include <math.h>

#define D_MODEL 1024
#define NHEADS  16
#define HEADD   64
#define NFREQ   32
#define BATCH   2
#define CSEQ    2048
#define NROWS   (BATCH*CSEQ)   // 4096

typedef _Float16 half8 __attribute__((ext_vector_type(8)));
typedef _Float16 half4v __attribute__((ext_vector_type(4)));
typedef float    f32x4 __attribute__((ext_vector_type(4)));

// async global->LDS, 16B per lane. dest is WAVE-UNIFORM base (HW adds lane*16).
__device__ __forceinline__ void async16(void* lds, const void* g)
{
    __builtin_amdgcn_global_load_lds((const __attribute__((address_space(1))) unsigned int*)g,
                                     (__attribute__((address_space(3))) unsigned int*)lds,
                                     16, 0, 0);
}

// ---------------------------------------------------------------------------
// cos/sin table (double precision mel to match numpy f64 -> f32 cast)
// ---------------------------------------------------------------------------
__global__ __launch_bounds__(256) void build_cs_kernel(float2* __restrict__ cs)
{
    int i = blockIdx.x * 256 + threadIdx.x;
    if (i >= CSEQ * NFREQ) return;
    int c = i >> 5, f = i & (NFREQ - 1);
    double mel_max = 2595.0 * log10(21.0);
    double step    = mel_max / (double)(NFREQ - 1);
    double freq    = 200.0 * (pow(10.0, step * (double)f / 2595.0) - 1.0) / 1000.0;
    float fr = (float)freq;
    float th = (float)c * fr;
    float s, co;
    sincosf(th, &s, &co);
    cs[i] = make_float2(co, s);
}

// ---------------------------------------------------------------------------
// Transpose + cast fp32 (R x C) -> fp16 (C x R)
// ---------------------------------------------------------------------------
__global__ __launch_bounds__(256) void transpose_cast_kernel(
    const float* __restrict__ in, _Float16* __restrict__ out, int R, int C)
{
    __shared__ float t[32][33];
    int bx = blockIdx.x * 32;
    int by = blockIdx.y * 32;
    int tx = threadIdx.x, ty = threadIdx.y;
    #pragma unroll
    for (int i = ty; i < 32; i += 8)
        t[i][tx] = in[(size_t)(by + i) * C + bx + tx];
    __syncthreads();
    #pragma unroll
    for (int i = ty; i < 32; i += 8)
        out[(size_t)(bx + i) * R + by + tx] = (_Float16)t[tx][i];
}

// ---------------------------------------------------------------------------
// Fused LN (shared stats for q-LN / kv-LN) + radius
// ---------------------------------------------------------------------------
__global__ __launch_bounds__(256) void ln_radius_kernel(
    const float* __restrict__ x,
    const float* __restrict__ gq,  const float* __restrict__ bq,
    const float* __restrict__ gkv, const float* __restrict__ bkv,
    const float* __restrict__ Wr,  const float* __restrict__ br,
    _Float16* __restrict__ xq, _Float16* __restrict__ xkv,
    float* __restrict__ radius)
{
    int row = blockIdx.x;
    const float* xr = x + (size_t)row * D_MODEL;
    int tid = threadIdx.x;
    float v[4];
    float s = 0.f, ss = 0.f, dr = 0.f;
    #pragma unroll
    for (int i = 0; i < 4; ++i) {
        int idx = tid + i * 256;
        float t = xr[idx];
        v[i] = t;
        s += t; ss += t * t; dr += t * Wr[idx];
    }
    #pragma unroll
    for (int off = 1; off < 64; off <<= 1) {
        s  += __shfl_xor(s, off);
        ss += __shfl_xor(ss, off);
        dr += __shfl_xor(dr, off);
    }
    __shared__ float red[3][4];
    int w = tid >> 6, lane = tid & 63;
    if (lane == 0) { red[0][w] = s; red[1][w] = ss; red[2][w] = dr; }
    __syncthreads();
    s  = red[0][0] + red[0][1] + red[0][2] + red[0][3];
    ss = red[1][0] + red[1][1] + red[1][2] + red[1][3];
    float mean = s * (1.f / D_MODEL);
    float var  = ss * (1.f / D_MODEL) - mean * mean;
    float rinv = rsqrtf(var + 1e-5f);
    #pragma unroll
    for (int i = 0; i < 4; ++i) {
        int idx = tid + i * 256;
        float xn = (v[i] - mean) * rinv;
        xq [(size_t)row * D_MODEL + idx] = (_Float16)(xn * gq[idx]  + bq[idx]);
        xkv[(size_t)row * D_MODEL + idx] = (_Float16)(xn * gkv[idx] + bkv[idx]);
    }
    if (tid == 0) {
        float drt = red[2][0] + red[2][1] + red[2][2] + red[2][3];
        float p = (drt + br[0]) * 0.01f;
        radius[row] = fminf(fmaxf(p, 0.5f), 2.0f);
    }
}

// ---------------------------------------------------------------------------
// GEMM: C = A * BT^T + bias. 128x128 tile, BK=32, global_load_lds staging.
// ---------------------------------------------------------------------------
#define BM 128
#define BN 128
#define BK 32

__global__ __launch_bounds__(256) void gemm_bt_f16(
    const _Float16* __restrict__ A,   // M x K
    const _Float16* __restrict__ BT,  // N x K
    const float* __restrict__ bias,   // N
    float* __restrict__ C,            // M x N
    int M, int N, int K)
{
    __shared__ _Float16 As[BM * BK];
    __shared__ _Float16 Bs[BN * BK];
    int tid = threadIdx.x;
    int lane = tid & 63, w = tid >> 6;
    int wm = w >> 1, wn = w & 1;
    int l15 = lane & 15, lg = lane >> 4;
    int bm = blockIdx.x * BM;
    int bn = blockIdx.y * BN;
    int lrow = lane >> 2;
    int lch  = lane & 3;
    f32x4 acc[4][4];
    f32x4 z = {0.f, 0.f, 0.f, 0.f};
    #pragma unroll
    for (int m = 0; m < 4; ++m)
        #pragma unroll
        for (int n = 0; n < 4; ++n) acc[m][n] = z;

    for (int k0 = 0; k0 < K; k0 += BK) {
        __syncthreads();
        #pragma unroll
        for (int i = 0; i < 2; ++i) {
            int seg = w * 2 + i;
            int row = seg * 16 + lrow;
            async16(&As[seg * 512], &A [(size_t)(bm + row) * K + k0 + lch * 8]);
            async16(&Bs[seg * 512], &BT[(size_t)(bn + row) * K + k0 + lch * 8]);
        }
        __syncthreads();
        half8 af[4], bf[4];
        #pragma unroll
        for (int m = 0; m < 4; ++m) af[m] = *(const half8*)&As[(wm * 64 + m * 16 + l15) * BK + lg * 8];
        #pragma unroll
        for (int n = 0; n < 4; ++n) bf[n] = *(const half8*)&Bs[(wn * 64 + n * 16 + l15) * BK + lg * 8];
        #pragma unroll
        for (int m = 0; m < 4; ++m)
            #pragma unroll
            for (int n = 0; n < 4; ++n)
                acc[m][n] = __builtin_amdgcn_mfma_f32_16x16x32_f16(af[m], bf[n], acc[m][n], 0, 0, 0);
    }

    #pragma unroll
    for (int m = 0; m < 4; ++m) {
        int row = bm + wm * 64 + m * 16 + lg * 4;
        #pragma unroll
        for (int n = 0; n < 4; ++n) {
            int col = bn + wn * 64 + n * 16 + l15;
            float bb = bias[col];
            #pragma unroll
            for (int r = 0; r < 4; ++r)
                C[(size_t)(row + r) * N + col] = acc[m][n][r] + bb;
        }
    }
}

// ---------------------------------------------------------------------------
// Fused RoPE + per-head LN (HD=64 == wave). q output pre-scaled by 1/sqrt(HD).
// ---------------------------------------------------------------------------
__global__ __launch_bounds__(256) void rope_headln_kernel(
    const float* __restrict__ q_raw,
    const float* __restrict__ kv_raw,
    const float* __restrict__ radius,
    const float2* __restrict__ cs_tab,
    const float* __restrict__ lnh_g, const float* __restrict__ lnh_b,
    _Float16* __restrict__ qn, _Float16* __restrict__ kn)
{
    int row = blockIdx.x;
    int b = row / CSEQ, c = row % CSEQ;
    int tid = threadIdx.x, lane = tid & 63, w = tid >> 6;
    float rr = radius[row];
    float2 cs = cs_tab[c * NFREQ + (lane >> 1)];
    float g = lnh_g[lane], bb = lnh_b[lane];

    #pragma unroll
    for (int hh = 0; hh < 4; ++hh) {
        int h = w * 4 + hh;
        size_t obase = ((size_t)(b * NHEADS + h) * CSEQ + c) * HEADD + lane;
        #pragma unroll
        for (int which = 0; which < 2; ++which) {
            float val = which == 0
                ? q_raw [(size_t)row * D_MODEL     + h * HEADD + lane]
                : kv_raw[(size_t)row * (2*D_MODEL) + h * HEADD + lane];
            float part = __shfl_xor(val, 1);
            float xr_ = (lane & 1) ? part : val;
            float xi_ = (lane & 1) ? val  : part;
            float rot = (lane & 1) ? rr * (xr_ * cs.y + xi_ * cs.x)
                                   : rr * (xr_ * cs.x - xi_ * cs.y);
            float s = rot;
            #pragma unroll
            for (int off = 1; off < 64; off <<= 1) s += __shfl_xor(s, off);
            float mean = s * (1.f / 64.f);
            float d = rot - mean;
            float ss = d * d;
            #pragma unroll
            for (int off = 1; off < 64; off <<= 1) ss += __shfl_xor(ss, off);
            float rinv = rsqrtf(ss * (1.f / 64.f) + 1e-5f);
            float ov = d * rinv * g + bb;
            if (which == 0) qn[obase] = (_Float16)(ov * 0.125f);  // fold 1/sqrt(64)
            else            kn[obase] = (_Float16)ov;
        }
    }
}

// ---------------------------------------------------------------------------
// V -> vT fp16 (B,H,HD,C)
// ---------------------------------------------------------------------------
__global__ __launch_bounds__(256) void v_transpose_kernel(
    const float* __restrict__ kv_raw, _Float16* __restrict__ vT)
{
    int bh = blockIdx.x >> 5;
    int c0 = (blockIdx.x & 31) * 64;
    int b = bh >> 4, h = bh & 15;
    __shared__ float t[64][65];
    int tid = threadIdx.x;
    int dcol = tid & 63, quarter = tid >> 6;
    for (int c = quarter; c < 64; c += 4)
        t[c][dcol] = kv_raw[(size_t)(b * CSEQ + c0 + c) * (2*D_MODEL) + D_MODEL + h * HEADD + dcol];
    __syncthreads();
    for (int d = quarter; d < 64; d += 4)
        vT[(size_t)(bh * HEADD + d) * CSEQ + c0 + dcol] = (_Float16)t[dcol][d];
}

// ---------------------------------------------------------------------------
// Flash attention v3: swapped QK^T (S^T accumulator: k = lg*4+r in-lane,
// q = l15), in-lane softmax (2 shfl/reduce), defer-max (THR=8), vectorized
// swizzled P stores, 4 waves x 16 q-rows, grid 1024, 40KB LDS -> 4 blocks/CU.
// ---------------------------------------------------------------------------
#define KVB 64
#define NT  (CSEQ / KVB)

__global__ __launch_bounds__(256, 4) void attn_kernel(
    const _Float16* __restrict__ qn, const _Float16* __restrict__ kn,
    const _Float16* __restrict__ vT, _Float16* __restrict__ o)
{
    __shared__ _Float16 KsB[2][KVB * 64];
    __shared__ _Float16 VsB[2][KVB * 64];
    __shared__ _Float16 P[4][16 * 64];
    int tid = threadIdx.x, lane = tid & 63, w = tid >> 6;
    int l15 = lane & 15, lg = lane >> 4;

    // bijective XCD-chunk swizzle (grid 1024, 1024 % 8 == 0)
    int orig = blockIdx.x;
    int wg   = (orig & 7) * 128 + (orig >> 3);
    int bh   = wg >> 5;
    int qc   = wg & 31;
    int q0   = qc * 64 + w * 16;

    const _Float16* qh = qn + (size_t)bh * CSEQ * HEADD;
    const _Float16* kh = kn + (size_t)bh * CSEQ * HEADD;
    const _Float16* vh = vT + (size_t)bh * HEADD * CSEQ;

    half8 aq[2];
    #pragma unroll
    for (int ks = 0; ks < 2; ++ks)
        aq[ks] = *(const half8*)&qh[(size_t)(q0 + l15) * HEADD + ks * 32 + lg * 8];

    f32x4 z = {0.f, 0.f, 0.f, 0.f};
    f32x4 oacc[4];               // [d4]; rows r hold q = lg*4+r
    #pragma unroll
    for (int d4 = 0; d4 < 4; ++d4) oacc[d4] = z;
    float mrun = -1e30f, lrun = 0.f;   // per q = l15 (duplicated across lg)

    int srow_in = lane >> 3;
    int csrc    = (lane & 7) ^ srow_in;
    int lsw     = l15 & 7;       // P chunk swizzle key

    auto stage = [&](int buf, int kt) {
        int k0 = kt * KVB;
        #pragma unroll
        for (int i = 0; i < 2; ++i) {
            int seg = w * 2 + i;
            int r = seg * 8 + srow_in;
            async16(&KsB[buf][seg * 512], &kh[(size_t)(k0 + r) * HEADD + csrc * 8]);
            async16(&VsB[buf][seg * 512], &vh[(size_t)r * CSEQ + k0 + csrc * 8]);
        }
    };

    stage(0, 0);
    __syncthreads();
    int cur = 0;

    for (int kt = 0; kt < NT; ++kt) {
        if (kt + 1 < NT) stage(cur ^ 1, kt + 1);

        // ---- S^T = K * Q^T : st[n] holds S^T[k = n*16+lg*4+r][q = l15] ----
        f32x4 st[4];
        #pragma unroll
        for (int n = 0; n < 4; ++n) st[n] = z;
        #pragma unroll
        for (int ks = 0; ks < 2; ++ks) {
            half8 ak[4];
            #pragma unroll
            for (int n = 0; n < 4; ++n) {
                int row = n * 16 + l15;
                int ch = (ks * 4 + lg) ^ (row & 7);
                ak[n] = *(const half8*)&KsB[cur][row * 64 + ch * 8];
            }
            #pragma unroll
            for (int n = 0; n < 4; ++n)
                st[n] = __builtin_amdgcn_mfma_f32_16x16x32_f16(ak[n], aq[ks], st[n], 0, 0, 0);
        }

        // ---- softmax over k: 16 in-lane values + 2 shfl ----
        float mx0 = fmaxf(fmaxf(st[0][0], st[0][1]), fmaxf(st[0][2], st[0][3]));
        float mx1 = fmaxf(fmaxf(st[1][0], st[1][1]), fmaxf(st[1][2], st[1][3]));
        float mx2 = fmaxf(fmaxf(st[2][0], st[2][1]), fmaxf(st[2][2], st[2][3]));
        float mx3 = fmaxf(fmaxf(st[3][0], st[3][1]), fmaxf(st[3][2], st[3][3]));
        float tmax = fmaxf(fmaxf(mx0, mx1), fmaxf(mx2, mx3));
        tmax = fmaxf(tmax, __shfl_xor(tmax, 16));
        tmax = fmaxf(tmax, __shfl_xor(tmax, 32));

        if (!__all(tmax <= mrun + 8.f)) {       // defer-max: rare path
            float nm = fmaxf(mrun, tmax);
            float sc = __expf(mrun - nm);
            mrun = nm;
            lrun *= sc;
            float scO[4];
            #pragma unroll
            for (int r = 0; r < 4; ++r) scO[r] = __shfl(sc, lg * 4 + r);
            #pragma unroll
            for (int d4 = 0; d4 < 4; ++d4)
                #pragma unroll
                for (int r = 0; r < 4; ++r) oacc[d4][r] *= scO[r];
        }

        float ps = 0.f;
        #pragma unroll
        for (int n = 0; n < 4; ++n)
            #pragma unroll
            for (int r = 0; r < 4; ++r) {
                float e = __expf(st[n][r] - mrun);
                st[n][r] = e;
                ps += e;
            }
        ps += __shfl_xor(ps, 16);
        ps += __shfl_xor(ps, 32);
        lrun += ps;

        // ---- P store: transposed layout P[q=l15][k], 16B-chunk XOR swizzle ----
        #pragma unroll
        for (int n = 0; n < 4; ++n) {
            half4v pk;
            #pragma unroll
            for (int r = 0; r < 4; ++r) pk[r] = (_Float16)st[n][r];
            int t  = n * 2 + (lg >> 1);
            int tp = t ^ lsw;
            *(half4v*)&P[w][l15 * 64 + tp * 8 + (lg & 1) * 4] = pk;
        }
        // wave-private P: no barrier needed

        // ---- PV: O[q][d] += P[q][k] * V^T[d][k] ----
        #pragma unroll
        for (int ks = 0; ks < 2; ++ks) {
            int tp2 = (ks * 4 + lg) ^ lsw;
            half8 ap = *(const half8*)&P[w][l15 * 64 + tp2 * 8];
            half8 bv[4];
            #pragma unroll
            for (int d4 = 0; d4 < 4; ++d4) {
                int row = d4 * 16 + l15;
                int ch = (ks * 4 + lg) ^ (row & 7);
                bv[d4] = *(const half8*)&VsB[cur][row * 64 + ch * 8];
            }
            #pragma unroll
            for (int d4 = 0; d4 < 4; ++d4)
                oacc[d4] = __builtin_amdgcn_mfma_f32_16x16x32_f16(ap, bv[d4], oacc[d4], 0, 0, 0);
        }

        __syncthreads();
        cur ^= 1;
    }

    // epilogue: move lrun (q=l15) to O-layout (q=lg*4+r), normalize, store
    int b = bh >> 4, h = bh & 15;
    #pragma unroll
    for (int r = 0; r < 4; ++r) {
        float lr = __shfl(lrun, lg * 4 + r);
        float inv = 1.f / lr;
        int c = q0 + lg * 4 + r;
        size_t base = ((size_t)b * CSEQ + c) * D_MODEL + h * HEADD;
        #pragma unroll
        for (int d4 = 0; d4 < 4; ++d4)
            o[base + d4 * 16 + l15] = (_Float16)(oacc[d4][r] * inv);
    }
}

// ---------------------------------------------------------------------------
extern "C" void kernel_launch(void* const* d_in, const int* in_sizes, int n_in,
                              void* d_out, int out_size, void* d_ws, size_t ws_size,
                              hipStream_t stream)
{
    (void)in_sizes; (void)n_in; (void)out_size; (void)ws_size;
    const float* x      = (const float*)d_in[0];
    const float* ln_q_g = (const float*)d_in[1];
    const float* ln_q_b = (const float*)d_in[2];
    const float* Wq     = (const float*)d_in[3];
    const float* bq     = (const float*)d_in[4];
    const float* ln_kv_g= (const float*)d_in[5];
    const float* ln_kv_b= (const float*)d_in[6];
    const float* Wkv    = (const float*)d_in[7];
    const float* bkv    = (const float*)d_in[8];
    const float* Wout   = (const float*)d_in[9];
    const float* bout   = (const float*)d_in[10];
    const float* lnh_g  = (const float*)d_in[11];
    const float* lnh_b  = (const float*)d_in[12];
    const float* Wr     = (const float*)d_in[13];
    const float* br     = (const float*)d_in[14];
    float* out = (float*)d_out;

    char* ws = (char*)d_ws;
    size_t off = 0;
    auto alloc = [&](size_t bytes) -> void* {
        void* p = ws + off;
        off += (bytes + 255) & ~(size_t)255;
        return p;
    };
    _Float16* WqT   = (_Float16*)alloc((size_t)D_MODEL * D_MODEL * 2);
    _Float16* WkvT  = (_Float16*)alloc((size_t)2 * D_MODEL * D_MODEL * 2);
    _Float16* WoutT = (_Float16*)alloc((size_t)D_MODEL * D_MODEL * 2);
    float*    radius= (float*)   alloc((size_t)NROWS * 4);
    float2*   cs_tab= (float2*)  alloc((size_t)CSEQ * NFREQ * 8);
    _Float16* vT    = (_Float16*)alloc((size_t)BATCH * NHEADS * HEADD * CSEQ * 2);
    float*    kv_raw= (float*)   alloc((size_t)NROWS * 2 * D_MODEL * 4);
    _Float16* xq    = (_Float16*)alloc((size_t)NROWS * D_MODEL * 2);
    _Float16* qn    = xq;
    _Float16* xkv   = (_Float16*)alloc((size_t)NROWS * D_MODEL * 2);
    _Float16* kn    = xkv;
    float*    q_raw = (float*)   alloc((size_t)NROWS * D_MODEL * 4);
    _Float16* o_h   = (_Float16*)q_raw;

    hipLaunchKernelGGL(build_cs_kernel, dim3(CSEQ * NFREQ / 256), dim3(256), 0, stream, cs_tab);
    hipLaunchKernelGGL(transpose_cast_kernel, dim3(D_MODEL/32, D_MODEL/32), dim3(32, 8), 0, stream,
                       Wq, WqT, D_MODEL, D_MODEL);
    hipLaunchKernelGGL(transpose_cast_kernel, dim3(2*D_MODEL/32, D_MODEL/32), dim3(32, 8), 0, stream,
                       Wkv, WkvT, D_MODEL, 2*D_MODEL);
    hipLaunchKernelGGL(transpose_cast_kernel, dim3(D_MODEL/32, D_MODEL/32), dim3(32, 8), 0, stream,
                       Wout, WoutT, D_MODEL, D_MODEL);
    hipLaunchKernelGGL(ln_radius_kernel, dim3(NROWS), dim3(256), 0, stream,
                       x, ln_q_g, ln_q_b, ln_kv_g, ln_kv_b, Wr, br, xq, xkv, radius);
    hipLaunchKernelGGL(gemm_bt_f16, dim3(NROWS/BM, D_MODEL/BN), dim3(256), 0, stream,
                       xq, WqT, bq, q_raw, NROWS, D_MODEL, D_MODEL);
    hipLaunchKernelGGL(gemm_bt_f16, dim3(NROWS/BM, 2*D_MODEL/BN), dim3(256), 0, stream,
                       xkv, WkvT, bkv, kv_raw, NROWS, 2*D_MODEL, D_MODEL);
    hipLaunchKernelGGL(rope_headln_kernel, dim3(NROWS), dim3(256), 0, stream,
                       q_raw, kv_raw, radius, cs_tab, lnh_g, lnh_b, qn, kn);
    hipLaunchKernelGGL(v_transpose_kernel, dim3(BATCH*NHEADS*CSEQ/64), dim3(256), 0, stream,
                       kv_raw, vT);
    hipLaunchKernelGGL(attn_kernel, dim3(BATCH*NHEADS*CSEQ/64), dim3(256), 0, stream,
                       qn, kn, vT, o_h);
    hipLaunchKernelGGL(gemm_bt_f16, dim3(NROWS/BM, D_MODEL/BN), dim3(256), 0, stream,
                       o_h, WoutT, bout, out, NROWS, D_MODEL, D_MODEL);
}

// Round 5
// 162.192 us; speedup vs baseline: 2.2427x; 1.2071x over previous
//
#include <hip/hip_runtime.h>
#include <math.h>

#define D_MODEL 1024
#define NHEADS  16
#define HEADD   64
#define NFREQ   32
#define BATCH   2
#define CSEQ    2048
#define NROWS   (BATCH*CSEQ)   // 4096

typedef _Float16 half8  __attribute__((ext_vector_type(8)));
typedef _Float16 half4v __attribute__((ext_vector_type(4)));
typedef float    f32x4  __attribute__((ext_vector_type(4)));

// async global->LDS, 16B per lane. dest is WAVE-UNIFORM base (HW adds lane*16).
__device__ __forceinline__ void async16(void* lds, const void* g)
{
    __builtin_amdgcn_global_load_lds((const __attribute__((address_space(1))) unsigned int*)g,
                                     (__attribute__((address_space(3))) unsigned int*)lds,
                                     16, 0, 0);
}

// ---------------------------------------------------------------------------
// cos/sin table (double precision mel to match numpy f64 -> f32 cast)
// ---------------------------------------------------------------------------
__global__ __launch_bounds__(256) void build_cs_kernel(float2* __restrict__ cs)
{
    int i = blockIdx.x * 256 + threadIdx.x;
    if (i >= CSEQ * NFREQ) return;
    int c = i >> 5, f = i & (NFREQ - 1);
    double mel_max = 2595.0 * log10(21.0);
    double step    = mel_max / (double)(NFREQ - 1);
    double freq    = 200.0 * (pow(10.0, step * (double)f / 2595.0) - 1.0) / 1000.0;
    float fr = (float)freq;
    float th = (float)c * fr;
    float s, co;
    sincosf(th, &s, &co);
    cs[i] = make_float2(co, s);
}

// ---------------------------------------------------------------------------
// Transpose + cast fp32 (R x C) -> fp16 (C x R)
// ---------------------------------------------------------------------------
__global__ __launch_bounds__(256) void transpose_cast_kernel(
    const float* __restrict__ in, _Float16* __restrict__ out, int R, int C)
{
    __shared__ float t[32][33];
    int bx = blockIdx.x * 32;
    int by = blockIdx.y * 32;
    int tx = threadIdx.x, ty = threadIdx.y;
    #pragma unroll
    for (int i = ty; i < 32; i += 8)
        t[i][tx] = in[(size_t)(by + i) * C + bx + tx];
    __syncthreads();
    #pragma unroll
    for (int i = ty; i < 32; i += 8)
        out[(size_t)(bx + i) * R + by + tx] = (_Float16)t[tx][i];
}

// ---------------------------------------------------------------------------
// Fused LN (shared stats) + radius, vectorized float4/half4
// ---------------------------------------------------------------------------
__global__ __launch_bounds__(256) void ln_radius_kernel(
    const float* __restrict__ x,
    const float* __restrict__ gq,  const float* __restrict__ bq,
    const float* __restrict__ gkv, const float* __restrict__ bkv,
    const float* __restrict__ Wr,  const float* __restrict__ br,
    _Float16* __restrict__ xq, _Float16* __restrict__ xkv,
    float* __restrict__ radius)
{
    int row = blockIdx.x;
    int tid = threadIdx.x;
    float4 xv = ((const float4*)(x + (size_t)row * D_MODEL))[tid];
    float4 wv = ((const float4*)Wr)[tid];
    float s  = xv.x + xv.y + xv.z + xv.w;
    float ss = xv.x*xv.x + xv.y*xv.y + xv.z*xv.z + xv.w*xv.w;
    float dr = xv.x*wv.x + xv.y*wv.y + xv.z*wv.z + xv.w*wv.w;
    #pragma unroll
    for (int off = 1; off < 64; off <<= 1) {
        s  += __shfl_xor(s, off);
        ss += __shfl_xor(ss, off);
        dr += __shfl_xor(dr, off);
    }
    __shared__ float red[3][4];
    int w = tid >> 6, lane = tid & 63;
    if (lane == 0) { red[0][w] = s; red[1][w] = ss; red[2][w] = dr; }
    __syncthreads();
    s  = red[0][0] + red[0][1] + red[0][2] + red[0][3];
    ss = red[1][0] + red[1][1] + red[1][2] + red[1][3];
    float mean = s * (1.f / D_MODEL);
    float var  = ss * (1.f / D_MODEL) - mean * mean;
    float rinv = rsqrtf(var + 1e-5f);
    float4 gqv = ((const float4*)gq)[tid],  bqv = ((const float4*)bq)[tid];
    float4 gkv4= ((const float4*)gkv)[tid], bkv4= ((const float4*)bkv)[tid];
    float xn0 = (xv.x - mean) * rinv, xn1 = (xv.y - mean) * rinv;
    float xn2 = (xv.z - mean) * rinv, xn3 = (xv.w - mean) * rinv;
    half4v q4 = { (_Float16)(xn0*gqv.x + bqv.x), (_Float16)(xn1*gqv.y + bqv.y),
                  (_Float16)(xn2*gqv.z + bqv.z), (_Float16)(xn3*gqv.w + bqv.w) };
    half4v k4 = { (_Float16)(xn0*gkv4.x + bkv4.x), (_Float16)(xn1*gkv4.y + bkv4.y),
                  (_Float16)(xn2*gkv4.z + bkv4.z), (_Float16)(xn3*gkv4.w + bkv4.w) };
    *(half4v*)&xq [(size_t)row * D_MODEL + tid * 4] = q4;
    *(half4v*)&xkv[(size_t)row * D_MODEL + tid * 4] = k4;
    if (tid == 0) {
        float drt = red[2][0] + red[2][1] + red[2][2] + red[2][3];
        float p = (drt + br[0]) * 0.01f;
        radius[row] = fminf(fmaxf(p, 0.5f), 2.0f);
    }
}

// ---------------------------------------------------------------------------
// GEMM core: 128x128 tile, BK=64, double-buffered global_load_lds with
// XOR-chunk pre-swizzled source, 1 barrier per K-step, 16x16x32 MFMA.
// As/Bs: [2][128*64] halves (16KB each buf).
// ---------------------------------------------------------------------------
__device__ __forceinline__ void gemm_core64(
    const _Float16* __restrict__ A, const _Float16* __restrict__ B,
    int bm, int bn, int K, _Float16* As, _Float16* Bs, f32x4 (*acc)[4])
{
    int tid = threadIdx.x, lane = tid & 63, w = tid >> 6;
    int wm = w >> 1, wn = w & 1;
    int l15 = lane & 15, lg = lane >> 4;
    int sr8 = lane >> 3;               // 0..7
    int csrc = (lane & 7) ^ sr8;       // pre-swizzled 16B source chunk

    auto stage = [&](int buf, int k0) {
        #pragma unroll
        for (int i = 0; i < 4; ++i) {
            int seg = w * 4 + i;       // 0..15, 8 rows each
            int row = seg * 8 + sr8;
            async16(&As[buf * 8192 + seg * 512], &A[(size_t)(bm + row) * K + k0 + csrc * 8]);
            async16(&Bs[buf * 8192 + seg * 512], &B[(size_t)(bn + row) * K + k0 + csrc * 8]);
        }
    };

    stage(0, 0);
    __syncthreads();
    int cur = 0;
    for (int k0 = 0; k0 < K; k0 += 64) {
        if (k0 + 64 < K) stage(cur ^ 1, k0 + 64);
        #pragma unroll
        for (int ks = 0; ks < 2; ++ks) {
            half8 af[4], bf[4];
            #pragma unroll
            for (int m = 0; m < 4; ++m) {
                int row = wm * 64 + m * 16 + l15;
                af[m] = *(const half8*)&As[cur * 8192 + row * 64 + ((ks * 4 + lg) ^ (row & 7)) * 8];
            }
            #pragma unroll
            for (int n = 0; n < 4; ++n) {
                int row = wn * 64 + n * 16 + l15;
                bf[n] = *(const half8*)&Bs[cur * 8192 + row * 64 + ((ks * 4 + lg) ^ (row & 7)) * 8];
            }
            #pragma unroll
            for (int m = 0; m < 4; ++m)
                #pragma unroll
                for (int n = 0; n < 4; ++n)
                    acc[m][n] = __builtin_amdgcn_mfma_f32_16x16x32_f16(af[m], bf[n], acc[m][n], 0, 0, 0);
        }
        __syncthreads();
        cur ^= 1;
    }
}

// ---------------------------------------------------------------------------
// Fused q+kv projection GEMM. Grid 768 (q: 256 blocks, kv: 512), XCD-swizzled.
// Epilogue: q/k cols -> bias + RoPE + head-LN -> qn/kn fp16 (B,H,C,HD);
// v cols -> bias -> v_rm fp16 row-major. q pre-scaled by 1/sqrt(HD).
// ---------------------------------------------------------------------------
__global__ __launch_bounds__(256) void gemm_qkv_kernel(
    const _Float16* __restrict__ xq,  const _Float16* __restrict__ xkv,
    const _Float16* __restrict__ WqT, const _Float16* __restrict__ WkvT,
    const float* __restrict__ bq,     const float* __restrict__ bkv,
    const float* __restrict__ radius, const float2* __restrict__ cs_tab,
    const float* __restrict__ lnh_g,  const float* __restrict__ lnh_b,
    _Float16* __restrict__ qn, _Float16* __restrict__ kn, _Float16* __restrict__ v_rm)
{
    __shared__ _Float16 As[2 * 8192];
    __shared__ _Float16 Bs[2 * 8192];
    int orig = blockIdx.x;
    int wg = (orig & 7) * 96 + (orig >> 3);   // bijective, 768 = 8*96

    const _Float16 *A, *Bt;
    const float* bias;
    int bm, bn;
    bool isq;
    if (wg < 256) { isq = true;  A = xq;  Bt = WqT;  bias = bq;
                    bm = (wg >> 3) * 128;  bn = (wg & 7) * 128; }
    else          { int t = wg - 256; isq = false; A = xkv; Bt = WkvT; bias = bkv;
                    bm = (t >> 4) * 128;   bn = (t & 15) * 128; }

    f32x4 acc[4][4];
    f32x4 z = {0.f, 0.f, 0.f, 0.f};
    #pragma unroll
    for (int m = 0; m < 4; ++m)
        #pragma unroll
        for (int n = 0; n < 4; ++n) acc[m][n] = z;

    gemm_core64(A, Bt, bm, bn, D_MODEL, As, Bs, acc);

    int tid = threadIdx.x, lane = tid & 63, w = tid >> 6;
    int wm = w >> 1, wn = w & 1;
    int l15 = lane & 15, lg = lane >> 4;
    int colbase = bn + wn * 64;

    float bb4[4];
    #pragma unroll
    for (int n = 0; n < 4; ++n) bb4[n] = bias[colbase + n * 16 + l15];

    if (!isq && colbase >= D_MODEL) {
        // ---- V epilogue: bias + fp16 row-major store ----
        int vcolb = colbase - D_MODEL;
        #pragma unroll
        for (int m = 0; m < 4; ++m)
            #pragma unroll
            for (int r = 0; r < 4; ++r) {
                int row = bm + wm * 64 + m * 16 + lg * 4 + r;
                #pragma unroll
                for (int n = 0; n < 4; ++n)
                    v_rm[(size_t)row * D_MODEL + vcolb + n * 16 + l15] =
                        (_Float16)(acc[m][n][r] + bb4[n]);
            }
        return;
    }

    // ---- q/k epilogue: bias + RoPE + head-LN ----
    float g4[4], bh4[4];
    #pragma unroll
    for (int n = 0; n < 4; ++n) {
        g4[n]  = lnh_g[n * 16 + l15];
        bh4[n] = lnh_b[n * 16 + l15];
    }
    int h = colbase >> 6;
    _Float16* dst = isq ? qn : kn;
    float qs = isq ? 0.125f : 1.f;
    bool im = (l15 & 1) != 0;

    #pragma unroll
    for (int m = 0; m < 4; ++m)
        #pragma unroll
        for (int r = 0; r < 4; ++r) {
            int row = bm + wm * 64 + m * 16 + lg * 4 + r;
            int b = row >> 11, c = row & (CSEQ - 1);
            float rr = radius[row];
            float vals[4];
            float s = 0.f, ss = 0.f;
            #pragma unroll
            for (int n = 0; n < 4; ++n) {
                float v0 = acc[m][n][r] + bb4[n];
                float pr = __shfl_xor(v0, 1);
                float2 cs = cs_tab[c * NFREQ + ((n * 16 + l15) >> 1)];
                float xr_ = im ? pr : v0;
                float xi_ = im ? v0 : pr;
                float rot = im ? rr * (xr_ * cs.y + xi_ * cs.x)
                               : rr * (xr_ * cs.x - xi_ * cs.y);
                vals[n] = rot;
                s += rot; ss += rot * rot;
            }
            #pragma unroll
            for (int off = 1; off < 16; off <<= 1) {
                s  += __shfl_xor(s, off);
                ss += __shfl_xor(ss, off);
            }
            float mean = s * (1.f / 64.f);
            float var  = ss * (1.f / 64.f) - mean * mean;
            float ri   = rsqrtf(var + 1e-5f);
            size_t base = ((size_t)(b * NHEADS + h) * CSEQ + c) * HEADD;
            #pragma unroll
            for (int n = 0; n < 4; ++n) {
                float o = ((vals[n] - mean) * ri * g4[n] + bh4[n]) * qs;
                dst[base + n * 16 + l15] = (_Float16)o;
            }
        }
}

// ---------------------------------------------------------------------------
// Output GEMM: o_h (fp16) x WoutT + bout -> f32 out. Grid 256, XCD-swizzled.
// ---------------------------------------------------------------------------
__global__ __launch_bounds__(256) void gemm_out_kernel(
    const _Float16* __restrict__ A, const _Float16* __restrict__ BT,
    const float* __restrict__ bias, float* __restrict__ C)
{
    __shared__ _Float16 As[2 * 8192];
    __shared__ _Float16 Bs[2 * 8192];
    int orig = blockIdx.x;
    int wg = (orig & 7) * 32 + (orig >> 3);   // 256 = 8*32
    int bm = (wg >> 3) * 128;
    int bn = (wg & 7) * 128;

    f32x4 acc[4][4];
    f32x4 z = {0.f, 0.f, 0.f, 0.f};
    #pragma unroll
    for (int m = 0; m < 4; ++m)
        #pragma unroll
        for (int n = 0; n < 4; ++n) acc[m][n] = z;

    gemm_core64(A, BT, bm, bn, D_MODEL, As, Bs, acc);

    int tid = threadIdx.x, lane = tid & 63, w = tid >> 6;
    int wm = w >> 1, wn = w & 1;
    int l15 = lane & 15, lg = lane >> 4;
    #pragma unroll
    for (int m = 0; m < 4; ++m) {
        int row = bm + wm * 64 + m * 16 + lg * 4;
        #pragma unroll
        for (int n = 0; n < 4; ++n) {
            int col = bn + wn * 64 + n * 16 + l15;
            float bb = bias[col];
            #pragma unroll
            for (int r = 0; r < 4; ++r)
                C[(size_t)(row + r) * D_MODEL + col] = acc[m][n][r] + bb;
        }
    }
}

// ---------------------------------------------------------------------------
// V row-major fp16 -> vT (B,H,HD,C) fp16
// ---------------------------------------------------------------------------
__global__ __launch_bounds__(256) void v_transpose_f16(
    const _Float16* __restrict__ v_rm, _Float16* __restrict__ vT)
{
    int bh = blockIdx.x >> 5;
    int c0 = (blockIdx.x & 31) * 64;
    int b = bh >> 4, h = bh & 15;
    __shared__ _Float16 t[64][68];
    int tid = threadIdx.x;
    int dcol = tid & 63, quarter = tid >> 6;
    for (int c = quarter; c < 64; c += 4)
        t[c][dcol] = v_rm[(size_t)(b * CSEQ + c0 + c) * D_MODEL + h * HEADD + dcol];
    __syncthreads();
    for (int d = quarter; d < 64; d += 4)
        vT[(size_t)(bh * HEADD + d) * CSEQ + c0 + dcol] = t[dcol][d];
}

// ---------------------------------------------------------------------------
// Flash attention (unchanged from R4): swapped QK^T, in-lane softmax,
// defer-max, swizzled P, 4 waves x 16 q-rows, grid 1024, 40KB LDS.
// ---------------------------------------------------------------------------
#define KVB 64
#define NT  (CSEQ / KVB)

__global__ __launch_bounds__(256, 4) void attn_kernel(
    const _Float16* __restrict__ qn, const _Float16* __restrict__ kn,
    const _Float16* __restrict__ vT, _Float16* __restrict__ o)
{
    __shared__ _Float16 KsB[2][KVB * 64];
    __shared__ _Float16 VsB[2][KVB * 64];
    __shared__ _Float16 P[4][16 * 64];
    int tid = threadIdx.x, lane = tid & 63, w = tid >> 6;
    int l15 = lane & 15, lg = lane >> 4;

    int orig = blockIdx.x;
    int wg   = (orig & 7) * 128 + (orig >> 3);
    int bh   = wg >> 5;
    int qc   = wg & 31;
    int q0   = qc * 64 + w * 16;

    const _Float16* qh = qn + (size_t)bh * CSEQ * HEADD;
    const _Float16* kh = kn + (size_t)bh * CSEQ * HEADD;
    const _Float16* vh = vT + (size_t)bh * HEADD * CSEQ;

    half8 aq[2];
    #pragma unroll
    for (int ks = 0; ks < 2; ++ks)
        aq[ks] = *(const half8*)&qh[(size_t)(q0 + l15) * HEADD + ks * 32 + lg * 8];

    f32x4 z = {0.f, 0.f, 0.f, 0.f};
    f32x4 oacc[4];
    #pragma unroll
    for (int d4 = 0; d4 < 4; ++d4) oacc[d4] = z;
    float mrun = -1e30f, lrun = 0.f;

    int srow_in = lane >> 3;
    int csrc    = (lane & 7) ^ srow_in;
    int lsw     = l15 & 7;

    auto stage = [&](int buf, int kt) {
        int k0 = kt * KVB;
        #pragma unroll
        for (int i = 0; i < 2; ++i) {
            int seg = w * 2 + i;
            int r = seg * 8 + srow_in;
            async16(&KsB[buf][seg * 512], &kh[(size_t)(k0 + r) * HEADD + csrc * 8]);
            async16(&VsB[buf][seg * 512], &vh[(size_t)r * CSEQ + k0 + csrc * 8]);
        }
    };

    stage(0, 0);
    __syncthreads();
    int cur = 0;

    for (int kt = 0; kt < NT; ++kt) {
        if (kt + 1 < NT) stage(cur ^ 1, kt + 1);

        f32x4 st[4];
        #pragma unroll
        for (int n = 0; n < 4; ++n) st[n] = z;
        #pragma unroll
        for (int ks = 0; ks < 2; ++ks) {
            half8 ak[4];
            #pragma unroll
            for (int n = 0; n < 4; ++n) {
                int row = n * 16 + l15;
                int ch = (ks * 4 + lg) ^ (row & 7);
                ak[n] = *(const half8*)&KsB[cur][row * 64 + ch * 8];
            }
            #pragma unroll
            for (int n = 0; n < 4; ++n)
                st[n] = __builtin_amdgcn_mfma_f32_16x16x32_f16(ak[n], aq[ks], st[n], 0, 0, 0);
        }

        float mx0 = fmaxf(fmaxf(st[0][0], st[0][1]), fmaxf(st[0][2], st[0][3]));
        float mx1 = fmaxf(fmaxf(st[1][0], st[1][1]), fmaxf(st[1][2], st[1][3]));
        float mx2 = fmaxf(fmaxf(st[2][0], st[2][1]), fmaxf(st[2][2], st[2][3]));
        float mx3 = fmaxf(fmaxf(st[3][0], st[3][1]), fmaxf(st[3][2], st[3][3]));
        float tmax = fmaxf(fmaxf(mx0, mx1), fmaxf(mx2, mx3));
        tmax = fmaxf(tmax, __shfl_xor(tmax, 16));
        tmax = fmaxf(tmax, __shfl_xor(tmax, 32));

        if (!__all(tmax <= mrun + 8.f)) {
            float nm = fmaxf(mrun, tmax);
            float sc = __expf(mrun - nm);
            mrun = nm;
            lrun *= sc;
            float scO[4];
            #pragma unroll
            for (int r = 0; r < 4; ++r) scO[r] = __shfl(sc, lg * 4 + r);
            #pragma unroll
            for (int d4 = 0; d4 < 4; ++d4)
                #pragma unroll
                for (int r = 0; r < 4; ++r) oacc[d4][r] *= scO[r];
        }

        float ps = 0.f;
        #pragma unroll
        for (int n = 0; n < 4; ++n)
            #pragma unroll
            for (int r = 0; r < 4; ++r) {
                float e = __expf(st[n][r] - mrun);
                st[n][r] = e;
                ps += e;
            }
        ps += __shfl_xor(ps, 16);
        ps += __shfl_xor(ps, 32);
        lrun += ps;

        #pragma unroll
        for (int n = 0; n < 4; ++n) {
            half4v pk;
            #pragma unroll
            for (int r = 0; r < 4; ++r) pk[r] = (_Float16)st[n][r];
            int t  = n * 2 + (lg >> 1);
            int tp = t ^ lsw;
            *(half4v*)&P[w][l15 * 64 + tp * 8 + (lg & 1) * 4] = pk;
        }

        #pragma unroll
        for (int ks = 0; ks < 2; ++ks) {
            int tp2 = (ks * 4 + lg) ^ lsw;
            half8 ap = *(const half8*)&P[w][l15 * 64 + tp2 * 8];
            half8 bv[4];
            #pragma unroll
            for (int d4 = 0; d4 < 4; ++d4) {
                int row = d4 * 16 + l15;
                int ch = (ks * 4 + lg) ^ (row & 7);
                bv[d4] = *(const half8*)&VsB[cur][row * 64 + ch * 8];
            }
            #pragma unroll
            for (int d4 = 0; d4 < 4; ++d4)
                oacc[d4] = __builtin_amdgcn_mfma_f32_16x16x32_f16(ap, bv[d4], oacc[d4], 0, 0, 0);
        }

        __syncthreads();
        cur ^= 1;
    }

    int b = bh >> 4, h = bh & 15;
    #pragma unroll
    for (int r = 0; r < 4; ++r) {
        float lr = __shfl(lrun, lg * 4 + r);
        float inv = 1.f / lr;
        int c = q0 + lg * 4 + r;
        size_t base = ((size_t)b * CSEQ + c) * D_MODEL + h * HEADD;
        #pragma unroll
        for (int d4 = 0; d4 < 4; ++d4)
            o[base + d4 * 16 + l15] = (_Float16)(oacc[d4][r] * inv);
    }
}

// ---------------------------------------------------------------------------
extern "C" void kernel_launch(void* const* d_in, const int* in_sizes, int n_in,
                              void* d_out, int out_size, void* d_ws, size_t ws_size,
                              hipStream_t stream)
{
    (void)in_sizes; (void)n_in; (void)out_size; (void)ws_size;
    const float* x      = (const float*)d_in[0];
    const float* ln_q_g = (const float*)d_in[1];
    const float* ln_q_b = (const float*)d_in[2];
    const float* Wq     = (const float*)d_in[3];
    const float* bq     = (const float*)d_in[4];
    const float* ln_kv_g= (const float*)d_in[5];
    const float* ln_kv_b= (const float*)d_in[6];
    const float* Wkv    = (const float*)d_in[7];
    const float* bkv    = (const float*)d_in[8];
    const float* Wout   = (const float*)d_in[9];
    const float* bout   = (const float*)d_in[10];
    const float* lnh_g  = (const float*)d_in[11];
    const float* lnh_b  = (const float*)d_in[12];
    const float* Wr     = (const float*)d_in[13];
    const float* br     = (const float*)d_in[14];
    float* out = (float*)d_out;

    char* ws = (char*)d_ws;
    size_t off = 0;
    auto alloc = [&](size_t bytes) -> void* {
        void* p = ws + off;
        off += (bytes + 255) & ~(size_t)255;
        return p;
    };
    _Float16* WqT   = (_Float16*)alloc((size_t)D_MODEL * D_MODEL * 2);
    _Float16* WkvT  = (_Float16*)alloc((size_t)2 * D_MODEL * D_MODEL * 2);
    _Float16* WoutT = (_Float16*)alloc((size_t)D_MODEL * D_MODEL * 2);
    float*    radius= (float*)   alloc((size_t)NROWS * 4);
    float2*   cs_tab= (float2*)  alloc((size_t)CSEQ * NFREQ * 8);
    _Float16* vT    = (_Float16*)alloc((size_t)BATCH * NHEADS * HEADD * CSEQ * 2);
    _Float16* v_rm  = (_Float16*)alloc((size_t)NROWS * D_MODEL * 2);
    _Float16* xq    = (_Float16*)alloc((size_t)NROWS * D_MODEL * 2);
    _Float16* xkv   = (_Float16*)alloc((size_t)NROWS * D_MODEL * 2);
    _Float16* qn    = (_Float16*)alloc((size_t)NROWS * D_MODEL * 2);
    _Float16* kn    = (_Float16*)alloc((size_t)NROWS * D_MODEL * 2);
    _Float16* o_h   = (_Float16*)alloc((size_t)NROWS * D_MODEL * 2);

    hipLaunchKernelGGL(build_cs_kernel, dim3(CSEQ * NFREQ / 256), dim3(256), 0, stream, cs_tab);
    hipLaunchKernelGGL(transpose_cast_kernel, dim3(D_MODEL/32, D_MODEL/32), dim3(32, 8), 0, stream,
                       Wq, WqT, D_MODEL, D_MODEL);
    hipLaunchKernelGGL(transpose_cast_kernel, dim3(2*D_MODEL/32, D_MODEL/32), dim3(32, 8), 0, stream,
                       Wkv, WkvT, D_MODEL, 2*D_MODEL);
    hipLaunchKernelGGL(transpose_cast_kernel, dim3(D_MODEL/32, D_MODEL/32), dim3(32, 8), 0, stream,
                       Wout, WoutT, D_MODEL, D_MODEL);
    hipLaunchKernelGGL(ln_radius_kernel, dim3(NROWS), dim3(256), 0, stream,
                       x, ln_q_g, ln_q_b, ln_kv_g, ln_kv_b, Wr, br, xq, xkv, radius);
    hipLaunchKernelGGL(gemm_qkv_kernel, dim3(768), dim3(256), 0, stream,
                       xq, xkv, WqT, WkvT, bq, bkv, radius, cs_tab, lnh_g, lnh_b,
                       qn, kn, v_rm);
    hipLaunchKernelGGL(v_transpose_f16, dim3(BATCH*NHEADS*CSEQ/64), dim3(256), 0, stream,
                       v_rm, vT);
    hipLaunchKernelGGL(attn_kernel, dim3(BATCH*NHEADS*CSEQ/64), dim3(256), 0, stream,
                       qn, kn, vT, o_h);
    hipLaunchKernelGGL(gemm_out_kernel, dim3(256), dim3(256), 0, stream,
                       o_h, WoutT, bout, out);
}

// Round 6
// 157.469 us; speedup vs baseline: 2.3099x; 1.0300x over previous
//
#include <hip/hip_runtime.h>
#include <math.h>

#define D_MODEL 1024
#define NHEADS  16
#define HEADD   64
#define NFREQ   32
#define BATCH   2
#define CSEQ    2048
#define NROWS   (BATCH*CSEQ)   // 4096
#define NQKV    (3*D_MODEL)    // 3072

typedef _Float16 half8  __attribute__((ext_vector_type(8)));
typedef _Float16 half4v __attribute__((ext_vector_type(4)));
typedef float    f32x4  __attribute__((ext_vector_type(4)));

// async global->LDS, 16B per lane. dest is WAVE-UNIFORM base (HW adds lane*16).
__device__ __forceinline__ void async16(void* lds, const void* g)
{
    __builtin_amdgcn_global_load_lds((const __attribute__((address_space(1))) unsigned int*)g,
                                     (__attribute__((address_space(3))) unsigned int*)lds,
                                     16, 0, 0);
}

// ---------------------------------------------------------------------------
// cos/sin table (double precision mel to match numpy f64 -> f32 cast)
// ---------------------------------------------------------------------------
__global__ __launch_bounds__(256) void build_cs_kernel(float2* __restrict__ cs)
{
    int i = blockIdx.x * 256 + threadIdx.x;
    if (i >= CSEQ * NFREQ) return;
    int c = i >> 5, f = i & (NFREQ - 1);
    double mel_max = 2595.0 * log10(21.0);
    double step    = mel_max / (double)(NFREQ - 1);
    double freq    = 200.0 * (pow(10.0, step * (double)f / 2595.0) - 1.0) / 1000.0;
    float fr = (float)freq;
    float th = (float)c * fr;
    float s, co;
    sincosf(th, &s, &co);
    cs[i] = make_float2(co, s);
}

// ---------------------------------------------------------------------------
// bias_eff init: [bq | bkv]
// ---------------------------------------------------------------------------
__global__ __launch_bounds__(256) void bias_init_kernel(
    const float* __restrict__ bq, const float* __restrict__ bkv, float* __restrict__ be)
{
    int i = blockIdx.x * 256 + threadIdx.x;
    if (i < D_MODEL) be[i] = bq[i];
    else if (i < NQKV) be[i] = bkv[i - D_MODEL];
}

// ---------------------------------------------------------------------------
// Transpose + optional row-scale (LN gain fold) + cast fp32(R x C)->fp16(C x R),
// and optional LN-bias fold: bias_acc[n] += sum_k bfold[k]*W[k][n] (atomicAdd).
// ---------------------------------------------------------------------------
__global__ __launch_bounds__(256) void transpose_fold_kernel(
    const float* __restrict__ in, _Float16* __restrict__ out, int R, int C,
    int rowoff, const float* __restrict__ scale,
    const float* __restrict__ bfold, float* __restrict__ bias_acc)
{
    __shared__ float t[32][33];
    __shared__ float part[4][32];
    int bx = blockIdx.x * 32;   // C (n) offset
    int by = blockIdx.y * 32;   // R (k) offset
    int tx = threadIdx.x, ty = threadIdx.y;
    #pragma unroll
    for (int i = ty; i < 32; i += 8)
        t[i][tx] = in[(size_t)(by + i) * C + bx + tx];
    __syncthreads();
    float sc = scale ? scale[by + tx] : 1.f;
    #pragma unroll
    for (int i = ty; i < 32; i += 8)
        out[(size_t)(rowoff + bx + i) * R + by + tx] = (_Float16)(t[tx][i] * sc);
    if (bfold) {
        float p = 0.f;
        #pragma unroll
        for (int i = ty; i < 32; i += 8)
            p += bfold[by + i] * t[i][tx];
        p += __shfl_xor(p, 32);           // combine ty pairs within wave
        if ((ty & 1) == 0) part[ty >> 1][tx] = p;
        __syncthreads();
        if (ty == 0)
            atomicAdd(&bias_acc[rowoff + bx + tx],
                      part[0][tx] + part[1][tx] + part[2][tx] + part[3][tx]);
    }
}

// ---------------------------------------------------------------------------
// LN stats + radius; writes xn fp16 (normalized, un-scaled: gains folded in W)
// ---------------------------------------------------------------------------
__global__ __launch_bounds__(256) void ln_radius_kernel(
    const float* __restrict__ x,
    const float* __restrict__ Wr,  const float* __restrict__ br,
    _Float16* __restrict__ xn, float* __restrict__ radius)
{
    int row = blockIdx.x;
    int tid = threadIdx.x;
    float4 xv = ((const float4*)(x + (size_t)row * D_MODEL))[tid];
    float4 wv = ((const float4*)Wr)[tid];
    float s  = xv.x + xv.y + xv.z + xv.w;
    float ss = xv.x*xv.x + xv.y*xv.y + xv.z*xv.z + xv.w*xv.w;
    float dr = xv.x*wv.x + xv.y*wv.y + xv.z*wv.z + xv.w*wv.w;
    #pragma unroll
    for (int off = 1; off < 64; off <<= 1) {
        s  += __shfl_xor(s, off);
        ss += __shfl_xor(ss, off);
        dr += __shfl_xor(dr, off);
    }
    __shared__ float red[3][4];
    int w = tid >> 6, lane = tid & 63;
    if (lane == 0) { red[0][w] = s; red[1][w] = ss; red[2][w] = dr; }
    __syncthreads();
    s  = red[0][0] + red[0][1] + red[0][2] + red[0][3];
    ss = red[1][0] + red[1][1] + red[1][2] + red[1][3];
    float mean = s * (1.f / D_MODEL);
    float var  = ss * (1.f / D_MODEL) - mean * mean;
    float rinv = rsqrtf(var + 1e-5f);
    half4v o4 = { (_Float16)((xv.x - mean) * rinv), (_Float16)((xv.y - mean) * rinv),
                  (_Float16)((xv.z - mean) * rinv), (_Float16)((xv.w - mean) * rinv) };
    *(half4v*)&xn[(size_t)row * D_MODEL + tid * 4] = o4;
    if (tid == 0) {
        float drt = red[2][0] + red[2][1] + red[2][2] + red[2][3];
        float p = (drt + br[0]) * 0.01f;
        radius[row] = fminf(fmaxf(p, 0.5f), 2.0f);
    }
}

// ---------------------------------------------------------------------------
// GEMM core: 128x128 tile, BK=32 double-buffered (16KB LDS total),
// global_load_lds staging, 1 barrier per K-step, 16 MFMA per step.
// [128][32] fp16 rows = 64B -> naturally conflict-balanced b128 reads.
// ---------------------------------------------------------------------------
__device__ __forceinline__ void gemm_core32(
    const _Float16* __restrict__ A, const _Float16* __restrict__ B,
    int bm, int bn, int K, _Float16* As, _Float16* Bs, f32x4 (*acc)[4])
{
    int tid = threadIdx.x, lane = tid & 63, w = tid >> 6;
    int wm = w >> 1, wn = w & 1;
    int l15 = lane & 15, lg = lane >> 4;
    int sr  = lane >> 2;      // 0..15 row within 16-row segment
    int sch = lane & 3;       // 16B chunk within 64B row

    auto stage = [&](int buf, int k0) {
        #pragma unroll
        for (int i = 0; i < 2; ++i) {
            int seg = w * 2 + i;                 // 0..7, 16 rows each
            int row = seg * 16 + sr;
            async16(&As[buf * 4096 + seg * 512], &A[(size_t)(bm + row) * K + k0 + sch * 8]);
            async16(&Bs[buf * 4096 + seg * 512], &B[(size_t)(bn + row) * K + k0 + sch * 8]);
        }
    };

    stage(0, 0);
    __syncthreads();
    int cur = 0;
    for (int k0 = 0; k0 < K; k0 += 32) {
        if (k0 + 32 < K) stage(cur ^ 1, k0 + 32);
        half8 af[4], bf[4];
        #pragma unroll
        for (int m = 0; m < 4; ++m)
            af[m] = *(const half8*)&As[cur * 4096 + (wm * 64 + m * 16 + l15) * 32 + lg * 8];
        #pragma unroll
        for (int n = 0; n < 4; ++n)
            bf[n] = *(const half8*)&Bs[cur * 4096 + (wn * 64 + n * 16 + l15) * 32 + lg * 8];
        #pragma unroll
        for (int m = 0; m < 4; ++m)
            #pragma unroll
            for (int n = 0; n < 4; ++n)
                acc[m][n] = __builtin_amdgcn_mfma_f32_16x16x32_f16(af[m], bf[n], acc[m][n], 0, 0, 0);
        __syncthreads();
        cur ^= 1;
    }
}

// ---------------------------------------------------------------------------
// Fused qkv GEMM: xn (M=4096 x K=1024) x WqkvT (N=3072) + bias_eff.
// Epilogue per column range: q -> RoPE+headLN (x0.125) -> qn; k -> same -> kn;
// v -> v_rm fp16 row-major.
// ---------------------------------------------------------------------------
__global__ __launch_bounds__(256, 4) void gemm_qkv_kernel(
    const _Float16* __restrict__ xn,  const _Float16* __restrict__ WT,
    const float* __restrict__ bias_eff,
    const float* __restrict__ radius, const float2* __restrict__ cs_tab,
    const float* __restrict__ lnh_g,  const float* __restrict__ lnh_b,
    _Float16* __restrict__ qn, _Float16* __restrict__ kn, _Float16* __restrict__ v_rm)
{
    __shared__ _Float16 As[2 * 4096];
    __shared__ _Float16 Bs[2 * 4096];
    int orig = blockIdx.x;
    int wg = (orig & 7) * 96 + (orig >> 3);   // bijective, 768 = 8*96
    int bm = (wg / 24) * 128;
    int bn = (wg % 24) * 128;

    f32x4 acc[4][4];
    f32x4 z = {0.f, 0.f, 0.f, 0.f};
    #pragma unroll
    for (int m = 0; m < 4; ++m)
        #pragma unroll
        for (int n = 0; n < 4; ++n) acc[m][n] = z;

    gemm_core32(xn, WT, bm, bn, D_MODEL, As, Bs, acc);

    int tid = threadIdx.x, lane = tid & 63, w = tid >> 6;
    int wm = w >> 1, wn = w & 1;
    int l15 = lane & 15, lg = lane >> 4;
    int colbase = bn + wn * 64;

    float bb4[4];
    #pragma unroll
    for (int n = 0; n < 4; ++n) bb4[n] = bias_eff[colbase + n * 16 + l15];

    if (colbase >= 2 * D_MODEL) {
        // ---- V epilogue ----
        int vcolb = colbase - 2 * D_MODEL;
        #pragma unroll
        for (int m = 0; m < 4; ++m)
            #pragma unroll
            for (int r = 0; r < 4; ++r) {
                int row = bm + wm * 64 + m * 16 + lg * 4 + r;
                #pragma unroll
                for (int n = 0; n < 4; ++n)
                    v_rm[(size_t)row * D_MODEL + vcolb + n * 16 + l15] =
                        (_Float16)(acc[m][n][r] + bb4[n]);
            }
        return;
    }

    // ---- q/k epilogue: bias + RoPE + head-LN ----
    bool isq = colbase < D_MODEL;
    int h = (colbase & (D_MODEL - 1)) >> 6;
    _Float16* dst = isq ? qn : kn;
    float qs = isq ? 0.125f : 1.f;
    bool im = (l15 & 1) != 0;

    float g4[4], bh4[4];
    #pragma unroll
    for (int n = 0; n < 4; ++n) {
        g4[n]  = lnh_g[n * 16 + l15];
        bh4[n] = lnh_b[n * 16 + l15];
    }

    #pragma unroll
    for (int m = 0; m < 4; ++m)
        #pragma unroll
        for (int r = 0; r < 4; ++r) {
            int row = bm + wm * 64 + m * 16 + lg * 4 + r;
            int b = row >> 11, c = row & (CSEQ - 1);
            float rr = radius[row];
            float vals[4];
            float s = 0.f, ss = 0.f;
            #pragma unroll
            for (int n = 0; n < 4; ++n) {
                float v0 = acc[m][n][r] + bb4[n];
                float pr = __shfl_xor(v0, 1);
                float2 cs = cs_tab[c * NFREQ + ((n * 16 + l15) >> 1)];
                float xr_ = im ? pr : v0;
                float xi_ = im ? v0 : pr;
                float rot = im ? rr * (xr_ * cs.y + xi_ * cs.x)
                               : rr * (xr_ * cs.x - xi_ * cs.y);
                vals[n] = rot;
                s += rot; ss += rot * rot;
            }
            #pragma unroll
            for (int off = 1; off < 16; off <<= 1) {
                s  += __shfl_xor(s, off);
                ss += __shfl_xor(ss, off);
            }
            float mean = s * (1.f / 64.f);
            float var  = ss * (1.f / 64.f) - mean * mean;
            float ri   = rsqrtf(var + 1e-5f);
            size_t base = ((size_t)(b * NHEADS + h) * CSEQ + c) * HEADD;
            #pragma unroll
            for (int n = 0; n < 4; ++n) {
                float o = ((vals[n] - mean) * ri * g4[n] + bh4[n]) * qs;
                dst[base + n * 16 + l15] = (_Float16)o;
            }
        }
}

// ---------------------------------------------------------------------------
// Output GEMM: o_h fp16 x WoutT + bout -> f32 out. Grid 256, XCD-swizzled.
// ---------------------------------------------------------------------------
__global__ __launch_bounds__(256, 4) void gemm_out_kernel(
    const _Float16* __restrict__ A, const _Float16* __restrict__ BT,
    const float* __restrict__ bias, float* __restrict__ C)
{
    __shared__ _Float16 As[2 * 4096];
    __shared__ _Float16 Bs[2 * 4096];
    int orig = blockIdx.x;
    int wg = (orig & 7) * 32 + (orig >> 3);   // 256 = 8*32
    int bm = (wg >> 3) * 128;
    int bn = (wg & 7) * 128;

    f32x4 acc[4][4];
    f32x4 z = {0.f, 0.f, 0.f, 0.f};
    #pragma unroll
    for (int m = 0; m < 4; ++m)
        #pragma unroll
        for (int n = 0; n < 4; ++n) acc[m][n] = z;

    gemm_core32(A, BT, bm, bn, D_MODEL, As, Bs, acc);

    int tid = threadIdx.x, lane = tid & 63, w = tid >> 6;
    int wm = w >> 1, wn = w & 1;
    int l15 = lane & 15, lg = lane >> 4;
    #pragma unroll
    for (int m = 0; m < 4; ++m) {
        int row = bm + wm * 64 + m * 16 + lg * 4;
        #pragma unroll
        for (int n = 0; n < 4; ++n) {
            int col = bn + wn * 64 + n * 16 + l15;
            float bb = bias[col];
            #pragma unroll
            for (int r = 0; r < 4; ++r)
                C[(size_t)(row + r) * D_MODEL + col] = acc[m][n][r] + bb;
        }
    }
}

// ---------------------------------------------------------------------------
// V row-major fp16 -> vT (B,H,HD,C) fp16
// ---------------------------------------------------------------------------
__global__ __launch_bounds__(256) void v_transpose_f16(
    const _Float16* __restrict__ v_rm, _Float16* __restrict__ vT)
{
    int bh = blockIdx.x >> 5;
    int c0 = (blockIdx.x & 31) * 64;
    int b = bh >> 4, h = bh & 15;
    __shared__ _Float16 t[64][68];
    int tid = threadIdx.x;
    int dcol = tid & 63, quarter = tid >> 6;
    for (int c = quarter; c < 64; c += 4)
        t[c][dcol] = v_rm[(size_t)(b * CSEQ + c0 + c) * D_MODEL + h * HEADD + dcol];
    __syncthreads();
    for (int d = quarter; d < 64; d += 4)
        vT[(size_t)(bh * HEADD + d) * CSEQ + c0 + dcol] = t[dcol][d];
}

// ---------------------------------------------------------------------------
// Flash attention (unchanged from R4/R5)
// ---------------------------------------------------------------------------
#define KVB 64
#define NT  (CSEQ / KVB)

__global__ __launch_bounds__(256, 4) void attn_kernel(
    const _Float16* __restrict__ qn, const _Float16* __restrict__ kn,
    const _Float16* __restrict__ vT, _Float16* __restrict__ o)
{
    __shared__ _Float16 KsB[2][KVB * 64];
    __shared__ _Float16 VsB[2][KVB * 64];
    __shared__ _Float16 P[4][16 * 64];
    int tid = threadIdx.x, lane = tid & 63, w = tid >> 6;
    int l15 = lane & 15, lg = lane >> 4;

    int orig = blockIdx.x;
    int wg   = (orig & 7) * 128 + (orig >> 3);
    int bh   = wg >> 5;
    int qc   = wg & 31;
    int q0   = qc * 64 + w * 16;

    const _Float16* qh = qn + (size_t)bh * CSEQ * HEADD;
    const _Float16* kh = kn + (size_t)bh * CSEQ * HEADD;
    const _Float16* vh = vT + (size_t)bh * HEADD * CSEQ;

    half8 aq[2];
    #pragma unroll
    for (int ks = 0; ks < 2; ++ks)
        aq[ks] = *(const half8*)&qh[(size_t)(q0 + l15) * HEADD + ks * 32 + lg * 8];

    f32x4 z = {0.f, 0.f, 0.f, 0.f};
    f32x4 oacc[4];
    #pragma unroll
    for (int d4 = 0; d4 < 4; ++d4) oacc[d4] = z;
    float mrun = -1e30f, lrun = 0.f;

    int srow_in = lane >> 3;
    int csrc    = (lane & 7) ^ srow_in;
    int lsw     = l15 & 7;

    auto stage = [&](int buf, int kt) {
        int k0 = kt * KVB;
        #pragma unroll
        for (int i = 0; i < 2; ++i) {
            int seg = w * 2 + i;
            int r = seg * 8 + srow_in;
            async16(&KsB[buf][seg * 512], &kh[(size_t)(k0 + r) * HEADD + csrc * 8]);
            async16(&VsB[buf][seg * 512], &vh[(size_t)r * CSEQ + k0 + csrc * 8]);
        }
    };

    stage(0, 0);
    __syncthreads();
    int cur = 0;

    for (int kt = 0; kt < NT; ++kt) {
        if (kt + 1 < NT) stage(cur ^ 1, kt + 1);

        f32x4 st[4];
        #pragma unroll
        for (int n = 0; n < 4; ++n) st[n] = z;
        #pragma unroll
        for (int ks = 0; ks < 2; ++ks) {
            half8 ak[4];
            #pragma unroll
            for (int n = 0; n < 4; ++n) {
                int row = n * 16 + l15;
                int ch = (ks * 4 + lg) ^ (row & 7);
                ak[n] = *(const half8*)&KsB[cur][row * 64 + ch * 8];
            }
            #pragma unroll
            for (int n = 0; n < 4; ++n)
                st[n] = __builtin_amdgcn_mfma_f32_16x16x32_f16(ak[n], aq[ks], st[n], 0, 0, 0);
        }

        float mx0 = fmaxf(fmaxf(st[0][0], st[0][1]), fmaxf(st[0][2], st[0][3]));
        float mx1 = fmaxf(fmaxf(st[1][0], st[1][1]), fmaxf(st[1][2], st[1][3]));
        float mx2 = fmaxf(fmaxf(st[2][0], st[2][1]), fmaxf(st[2][2], st[2][3]));
        float mx3 = fmaxf(fmaxf(st[3][0], st[3][1]), fmaxf(st[3][2], st[3][3]));
        float tmax = fmaxf(fmaxf(mx0, mx1), fmaxf(mx2, mx3));
        tmax = fmaxf(tmax, __shfl_xor(tmax, 16));
        tmax = fmaxf(tmax, __shfl_xor(tmax, 32));

        if (!__all(tmax <= mrun + 8.f)) {
            float nm = fmaxf(mrun, tmax);
            float sc = __expf(mrun - nm);
            mrun = nm;
            lrun *= sc;
            float scO[4];
            #pragma unroll
            for (int r = 0; r < 4; ++r) scO[r] = __shfl(sc, lg * 4 + r);
            #pragma unroll
            for (int d4 = 0; d4 < 4; ++d4)
                #pragma unroll
                for (int r = 0; r < 4; ++r) oacc[d4][r] *= scO[r];
        }

        float ps = 0.f;
        #pragma unroll
        for (int n = 0; n < 4; ++n)
            #pragma unroll
            for (int r = 0; r < 4; ++r) {
                float e = __expf(st[n][r] - mrun);
                st[n][r] = e;
                ps += e;
            }
        ps += __shfl_xor(ps, 16);
        ps += __shfl_xor(ps, 32);
        lrun += ps;

        #pragma unroll
        for (int n = 0; n < 4; ++n) {
            half4v pk;
            #pragma unroll
            for (int r = 0; r < 4; ++r) pk[r] = (_Float16)st[n][r];
            int t  = n * 2 + (lg >> 1);
            int tp = t ^ lsw;
            *(half4v*)&P[w][l15 * 64 + tp * 8 + (lg & 1) * 4] = pk;
        }

        #pragma unroll
        for (int ks = 0; ks < 2; ++ks) {
            int tp2 = (ks * 4 + lg) ^ lsw;
            half8 ap = *(const half8*)&P[w][l15 * 64 + tp2 * 8];
            half8 bv[4];
            #pragma unroll
            for (int d4 = 0; d4 < 4; ++d4) {
                int row = d4 * 16 + l15;
                int ch = (ks * 4 + lg) ^ (row & 7);
                bv[d4] = *(const half8*)&VsB[cur][row * 64 + ch * 8];
            }
            #pragma unroll
            for (int d4 = 0; d4 < 4; ++d4)
                oacc[d4] = __builtin_amdgcn_mfma_f32_16x16x32_f16(ap, bv[d4], oacc[d4], 0, 0, 0);
        }

        __syncthreads();
        cur ^= 1;
    }

    int b = bh >> 4, h = bh & 15;
    #pragma unroll
    for (int r = 0; r < 4; ++r) {
        float lr = __shfl(lrun, lg * 4 + r);
        float inv = 1.f / lr;
        int c = q0 + lg * 4 + r;
        size_t base = ((size_t)b * CSEQ + c) * D_MODEL + h * HEADD;
        #pragma unroll
        for (int d4 = 0; d4 < 4; ++d4)
            o[base + d4 * 16 + l15] = (_Float16)(oacc[d4][r] * inv);
    }
}

// ---------------------------------------------------------------------------
extern "C" void kernel_launch(void* const* d_in, const int* in_sizes, int n_in,
                              void* d_out, int out_size, void* d_ws, size_t ws_size,
                              hipStream_t stream)
{
    (void)in_sizes; (void)n_in; (void)out_size; (void)ws_size;
    const float* x      = (const float*)d_in[0];
    const float* ln_q_g = (const float*)d_in[1];
    const float* ln_q_b = (const float*)d_in[2];
    const float* Wq     = (const float*)d_in[3];
    const float* bq     = (const float*)d_in[4];
    const float* ln_kv_g= (const float*)d_in[5];
    const float* ln_kv_b= (const float*)d_in[6];
    const float* Wkv    = (const float*)d_in[7];
    const float* bkv    = (const float*)d_in[8];
    const float* Wout   = (const float*)d_in[9];
    const float* bout   = (const float*)d_in[10];
    const float* lnh_g  = (const float*)d_in[11];
    const float* lnh_b  = (const float*)d_in[12];
    const float* Wr     = (const float*)d_in[13];
    const float* br     = (const float*)d_in[14];
    float* out = (float*)d_out;

    char* ws = (char*)d_ws;
    size_t off = 0;
    auto alloc = [&](size_t bytes) -> void* {
        void* p = ws + off;
        off += (bytes + 255) & ~(size_t)255;
        return p;
    };
    _Float16* WqkvT  = (_Float16*)alloc((size_t)NQKV * D_MODEL * 2);
    _Float16* WoutT  = (_Float16*)alloc((size_t)D_MODEL * D_MODEL * 2);
    float*    bias_e = (float*)   alloc((size_t)NQKV * 4);
    float*    radius = (float*)   alloc((size_t)NROWS * 4);
    float2*   cs_tab = (float2*)  alloc((size_t)CSEQ * NFREQ * 8);
    _Float16* vT     = (_Float16*)alloc((size_t)BATCH * NHEADS * HEADD * CSEQ * 2);
    _Float16* v_rm   = (_Float16*)alloc((size_t)NROWS * D_MODEL * 2);
    _Float16* xn     = (_Float16*)alloc((size_t)NROWS * D_MODEL * 2);
    _Float16* qn     = (_Float16*)alloc((size_t)NROWS * D_MODEL * 2);
    _Float16* kn     = (_Float16*)alloc((size_t)NROWS * D_MODEL * 2);
    _Float16* o_h    = (_Float16*)alloc((size_t)NROWS * D_MODEL * 2);

    hipLaunchKernelGGL(bias_init_kernel, dim3(NQKV / 256), dim3(256), 0, stream, bq, bkv, bias_e);
    hipLaunchKernelGGL(build_cs_kernel, dim3(CSEQ * NFREQ / 256), dim3(256), 0, stream, cs_tab);
    // WqkvT rows 0..1023 = diag(gq)Wq ; rows 1024..3071 = diag(gkv)Wkv
    hipLaunchKernelGGL(transpose_fold_kernel, dim3(D_MODEL/32, D_MODEL/32), dim3(32, 8), 0, stream,
                       Wq, WqkvT, D_MODEL, D_MODEL, 0, ln_q_g, ln_q_b, bias_e);
    hipLaunchKernelGGL(transpose_fold_kernel, dim3(2*D_MODEL/32, D_MODEL/32), dim3(32, 8), 0, stream,
                       Wkv, WqkvT, D_MODEL, 2*D_MODEL, D_MODEL, ln_kv_g, ln_kv_b, bias_e);
    hipLaunchKernelGGL(transpose_fold_kernel, dim3(D_MODEL/32, D_MODEL/32), dim3(32, 8), 0, stream,
                       Wout, WoutT, D_MODEL, D_MODEL, 0, (const float*)nullptr,
                       (const float*)nullptr, (float*)nullptr);
    hipLaunchKernelGGL(ln_radius_kernel, dim3(NROWS), dim3(256), 0, stream,
                       x, Wr, br, xn, radius);
    hipLaunchKernelGGL(gemm_qkv_kernel, dim3(768), dim3(256), 0, stream,
                       xn, WqkvT, bias_e, radius, cs_tab, lnh_g, lnh_b, qn, kn, v_rm);
    hipLaunchKernelGGL(v_transpose_f16, dim3(BATCH*NHEADS*CSEQ/64), dim3(256), 0, stream,
                       v_rm, vT);
    hipLaunchKernelGGL(attn_kernel, dim3(BATCH*NHEADS*CSEQ/64), dim3(256), 0, stream,
                       qn, kn, vT, o_h);
    hipLaunchKernelGGL(gemm_out_kernel, dim3(256), dim3(256), 0, stream,
                       o_h, WoutT, bout, out);
}